// Round 2
// baseline (343.692 us; speedup 1.0000x reference)
//
#include <hip/hip_runtime.h>
#include <stdint.h>

#define NROW 256
#define NV   128000
#define NV4  (NV / 4)
#define NBIN 7680
#define NCH  8
#define BLO  0x42300000u     // bits of 44.0f
#define BSH  10
#define GCAP 4096
#define LOG2E 1.44269504088896340736f
#define SLICES 4
#define TPB1 256
#define TPB2 1024
#define SLICE_F4 (NV4 / SLICES)   // 8000

// ---- workspace layout (bytes) ----
#define WS_HIST   0
#define HIST_BYTES ((size_t)NROW * NBIN * 4)            // 7,864,320
#define WS_GCNT   (HIST_BYTES)                          // 256*4
#define WS_BEST   (WS_GCNT + NROW * 4)                  // 256*8
#define WS_PARAMS (WS_BEST + NROW * 8)                  // 256*16
#define WS_GATHER (WS_PARAMS + NROW * 16)               // 256*GCAP*8
#define WS_NEEDED (WS_GATHER + (size_t)NROW * GCAP * 8)
#define MEMSET_BYTES (WS_PARAMS)                        // hist + gcnt + best

struct RowParams { int bstar; float A; float P; int pad; };

__device__ __forceinline__ float t_hi() { return __uint_as_float(0x42A7FFFFu); } // ~83.99999

// monotone race key: log2(p/noise) + const = s*log2e - log2(-log2 u) + const
__device__ __forceinline__ unsigned long long race_key(float s, float u, unsigned idx) {
    float nl  = -__builtin_amdgcn_logf(u);       // -log2(u) > 0
    float l2n = __builtin_amdgcn_logf(nl);       // log2(-log2 u)
    float keyf = fmaf(s, LOG2E, -l2n);
    unsigned kb = __float_as_uint(keyf);
    kb ^= ((unsigned)((int)kb >> 31)) | 0x80000000u;   // ordered-float transform
    return ((unsigned long long)kb << 32) | (unsigned)(~idx);
}

// ---------------- K1: per-slice LDS histogram -> global merge ----------------
__global__ __launch_bounds__(TPB1)
void k1_hist(const float* __restrict__ logits, const float* __restrict__ temps,
             float* __restrict__ hist)
{
    __shared__ float lh[NBIN];
    const int row = blockIdx.x >> 2;
    const int sl  = blockIdx.x & 3;
    for (int b = threadIdx.x; b < NBIN; b += TPB1) lh[b] = 0.0f;
    __syncthreads();
    const float invT = 1.0f / temps[row];
    const float4* __restrict__ l4 =
        (const float4*)(logits + (size_t)row * NV) + sl * SLICE_F4;
    for (int v = threadIdx.x; v < SLICE_F4; v += TPB1) {
        float4 x = l4[v];
        float xs[4] = {x.x, x.y, x.z, x.w};
        #pragma unroll
        for (int c = 0; c < 4; ++c) {
            float s = xs[c] * invT;
            float t = s + 64.0f;
            float tc = fminf(fmaxf(t, 44.0f), t_hi());
            int bin = (int)((__float_as_uint(tc) - BLO) >> BSH);
            float q = __builtin_amdgcn_exp2f(fmaf(s, LOG2E, -20.0f)); // exp(s)*2^-20
            atomicAdd(&lh[bin], q);
        }
    }
    __syncthreads();
    float* __restrict__ gh = hist + (size_t)row * NBIN;
    for (int b = threadIdx.x; b < NBIN; b += TPB1) {
        float v = lh[b];
        if (v != 0.0f) atomicAdd(&gh[b], v);
    }
}

// ---------------- K2: per-row suffix scan -> bstar, A, P ---------------------
__global__ __launch_bounds__(TPB2)
void k2_scan(const float* __restrict__ hist, const float* __restrict__ topps,
             RowParams* __restrict__ params)
{
    __shared__ float qm[NBIN];
    __shared__ float ct[TPB2];
    __shared__ float ct2[TPB2];
    __shared__ unsigned long long sh_cross;
    const int row = blockIdx.x, tid = threadIdx.x;
    const float* __restrict__ gh = hist + (size_t)row * NBIN;
    for (int b = tid; b < NBIN; b += TPB2) qm[b] = gh[b];
    if (tid == 0) sh_cross = 0ull;
    __syncthreads();

    const int b0 = tid * NCH;
    float chs = 0.0f;
    #pragma unroll
    for (int i2 = 0; i2 < NCH; ++i2) {
        int b = b0 + i2;
        if (b < NBIN) chs += qm[b];
    }
    ct[tid] = chs;
    __syncthreads();
    float* src = ct; float* dst = ct2;
    for (int d = 1; d < TPB2; d <<= 1) {       // suffix-inclusive scan
        float val = src[tid] + ((tid + d < TPB2) ? src[tid + d] : 0.0f);
        dst[tid] = val;
        __syncthreads();
        float* tm = src; src = dst; dst = tm;
    }
    const float Zq = src[0];
    const float P = topps[row] * Zq;
    {
        float mine = src[tid];
        float nxt = (tid + 1 < TPB2) ? src[tid + 1] : 0.0f;
        if (mine > P && nxt <= P)
            atomicMax(&sh_cross, ((unsigned long long)(tid + 1) << 32));
    }
    __syncthreads();
    if (tid == 0) {
        RowParams rp; rp.pad = 0; rp.P = P;
        if (sh_cross == 0ull) {
            rp.bstar = -1000000; rp.A = 0.0f;      // keep everything
        } else {
            int cstar = (int)(sh_cross >> 32) - 1;
            float run = (cstar + 1 < TPB2) ? src[cstar + 1] : 0.0f;
            int bst = -1; float abv = run;
            for (int i2 = NCH - 1; i2 >= 0; --i2) {
                int b = cstar * NCH + i2;
                if (b >= NBIN) continue;
                float inc = qm[b];
                if (run <= P && run + inc > P) { bst = b; abv = run; break; }
                run += inc;
            }
            if (bst < 0) { bst = cstar * NCH; abv = run; }
            rp.bstar = bst;
            rp.A = abv;                            // mass of bins >= bstar+1
        }
        params[row] = rp;
    }
}

// ---------------- K3: per-slice race over kept + boundary gather -------------
__global__ __launch_bounds__(TPB1)
void k3_race(const float* __restrict__ logits, const float* __restrict__ temps,
             const float* __restrict__ unoise, const RowParams* __restrict__ params,
             unsigned long long* __restrict__ best, unsigned int* __restrict__ gcnt,
             unsigned long long* __restrict__ gather)
{
    const int row = blockIdx.x >> 2;
    const int sl  = blockIdx.x & 3;
    const int tid = threadIdx.x;
    const RowParams rp = params[row];
    const int bstar = rp.bstar;
    const float invT = 1.0f / temps[row];
    const float4* __restrict__ l4 =
        (const float4*)(logits + (size_t)row * NV) + sl * SLICE_F4;
    const float4* __restrict__ u4 =
        (const float4*)(unoise + (size_t)row * NV) + sl * SLICE_F4;
    unsigned long long* __restrict__ grow = gather + (size_t)row * GCAP;
    const int ibase = sl * SLICE_F4 * 4;
    unsigned long long mybest = 0ull;
    for (int v = tid; v < SLICE_F4; v += TPB1) {
        float4 x = l4[v];
        float4 uu = u4[v];
        float xs[4] = {x.x, x.y, x.z, x.w};
        float us[4] = {uu.x, uu.y, uu.z, uu.w};
        #pragma unroll
        for (int c = 0; c < 4; ++c) {
            float s = xs[c] * invT;
            float t = s + 64.0f;
            float tc = fminf(fmaxf(t, 44.0f), t_hi());
            int bin = (int)((__float_as_uint(tc) - BLO) >> BSH);
            unsigned idx = (unsigned)(ibase + v * 4 + c);
            if (bin > bstar) {                      // definitely in nucleus
                unsigned long long key = race_key(s, us[c], idx);
                if (key > mybest) mybest = key;
            } else if (bin >= bstar - 1) {          // boundary bins {bstar-1, bstar}
                float q = __builtin_amdgcn_exp2f(fmaf(s, LOG2E, -20.0f));
                unsigned pos = atomicAdd(&gcnt[row], 1u);
                if (pos < GCAP)
                    grow[pos] = ((unsigned long long)__float_as_uint(q) << 32)
                              | (unsigned)(~idx);
            }
        }
    }
    // block reduction of mybest
    #pragma unroll
    for (int o = 32; o > 0; o >>= 1) {
        unsigned long long other = __shfl_down(mybest, o, 64);
        if (other > mybest) mybest = other;
    }
    __shared__ unsigned long long wb[TPB1 / 64];
    if ((tid & 63) == 0) wb[tid >> 6] = mybest;
    __syncthreads();
    if (tid == 0) {
        unsigned long long m2 = wb[0];
        #pragma unroll
        for (int w = 1; w < TPB1 / 64; ++w) if (wb[w] > m2) m2 = wb[w];
        if (m2) atomicMax(&best[row], m2);
    }
}

// ---------------- K4: per-row sort boundary, exact cut, final winner ---------
__global__ __launch_bounds__(TPB2)
void k4_final(const float* __restrict__ logits, const float* __restrict__ temps,
              const float* __restrict__ unoise, const RowParams* __restrict__ params,
              const unsigned long long* __restrict__ best,
              const unsigned int* __restrict__ gcnt,
              const unsigned long long* __restrict__ gather, int* __restrict__ out)
{
    __shared__ unsigned long long gk[GCAP];
    __shared__ float sa[GCAP];
    __shared__ float sb[GCAP];
    __shared__ int sh_kst;
    __shared__ unsigned long long sh_best;
    const int row = blockIdx.x, tid = threadIdx.x;
    const RowParams rp = params[row];
    unsigned int ngu = gcnt[row];
    if (ngu > GCAP) ngu = GCAP;
    const int ng = (int)ngu;
    if (tid == 0) { sh_kst = 0; sh_best = best[row]; }
    if (ng > 0) {
        int N2 = 64; while (N2 < ng) N2 <<= 1;
        const unsigned long long* __restrict__ grow = gather + (size_t)row * GCAP;
        for (int i = tid; i < N2; i += TPB2) gk[i] = (i < ng) ? grow[i] : 0ull;
        __syncthreads();
        // bitonic sort descending on (qbits, ~idx)
        for (int k = 2; k <= N2; k <<= 1) {
            for (int j = k >> 1; j > 0; j >>= 1) {
                for (int i = tid; i < N2; i += TPB2) {
                    int ixj = i ^ j;
                    if (ixj > i) {
                        unsigned long long a = gk[i], b = gk[ixj];
                        bool up = ((i & k) == 0);
                        if (up ? (a < b) : (a > b)) { gk[i] = b; gk[ixj] = a; }
                    }
                }
                __syncthreads();
            }
        }
        // inclusive prefix scan of q
        for (int i = tid; i < N2; i += TPB2)
            sa[i] = __uint_as_float((unsigned)(gk[i] >> 32));
        __syncthreads();
        float* ssrc = sa; float* sdst = sb;
        for (int d = 1; d < N2; d <<= 1) {
            for (int i = tid; i < N2; i += TPB2)
                sdst[i] = ssrc[i] + ((i >= d) ? ssrc[i - d] : 0.0f);
            __syncthreads();
            float* tm = ssrc; ssrc = sdst; sdst = tm;
        }
        for (int i = tid; i < ng; i += TPB2) {
            float excl = rp.A + ((i == 0) ? 0.0f : ssrc[i - 1]);
            if (excl <= rp.P) atomicMax(&sh_kst, i + 1);
        }
        __syncthreads();
        const int kst = sh_kst;
        const float* __restrict__ lrow = logits + (size_t)row * NV;
        const float* __restrict__ urow = unoise + (size_t)row * NV;
        const float invT = 1.0f / temps[row];
        unsigned long long gb = 0ull;
        for (int i = tid; i < kst; i += TPB2) {
            unsigned idx = ~(unsigned)(gk[i] & 0xFFFFFFFFull);
            float s = lrow[idx] * invT;
            unsigned long long key = race_key(s, urow[idx], idx);
            if (key > gb) gb = key;
        }
        #pragma unroll
        for (int o = 32; o > 0; o >>= 1) {
            unsigned long long other = __shfl_down(gb, o, 64);
            if (other > gb) gb = other;
        }
        if ((tid & 63) == 0 && gb) atomicMax(&sh_best, gb);
        __syncthreads();
    }
    if (tid == 0) out[row] = (int)(~(unsigned)(sh_best & 0xFFFFFFFFull));
}

// =================== fallback: proven round-1 single kernel ==================
#define ONT 1024
__global__ __launch_bounds__(ONT, 1)
void sampler_fallback(const float* __restrict__ logits,
                      const float* __restrict__ temps,
                      const float* __restrict__ topps,
                      const float* __restrict__ unoise,
                      int* __restrict__ out)
{
    __shared__ float qmass[NBIN];
    __shared__ float ct[ONT];
    __shared__ float ct2[ONT];
    __shared__ unsigned long long gkeys[GCAP];
    __shared__ float sa[GCAP];
    __shared__ float sb[GCAP];
    __shared__ float wred[16];
    __shared__ unsigned long long sh_cross;
    __shared__ unsigned long long sh_best;
    __shared__ unsigned int gcnt;
    __shared__ int sh_bstar;
    __shared__ float sh_A;
    __shared__ float sh_m;
    __shared__ float sh_Zq;
    __shared__ int sh_kstar;

    const int row = blockIdx.x;
    const int tid = threadIdx.x;
    const float* __restrict__ lrow = logits + (size_t)row * NV;
    const float* __restrict__ urow = unoise + (size_t)row * NV;
    const float invT = 1.0f / temps[row];
    const float topp = topps[row];

    for (int b = tid; b < NBIN; b += ONT) qmass[b] = 0.0f;
    if (tid == 0) { sh_cross = 0ull; sh_best = 0ull; gcnt = 0u; sh_kstar = 0; sh_bstar = 0; sh_A = 0.0f; }
    __syncthreads();

    const float4* __restrict__ l4 = (const float4*)lrow;
    float mloc = -3.402823466e38f;
    const float qscale = 9.5367431640625e-07f;
    for (int v = tid; v < NV4; v += ONT) {
        float4 x = l4[v];
        float xs[4] = {x.x, x.y, x.z, x.w};
        #pragma unroll
        for (int c = 0; c < 4; ++c) {
            float s = xs[c] * invT;
            mloc = fmaxf(mloc, s);
            float q = __expf(s) * qscale;
            float t = fminf(fmaxf(s + 64.0f, 44.0f), 84.0f);
            int bin = (int)((__float_as_uint(t) - BLO) >> BSH);
            bin = min(bin, NBIN - 1);
            atomicAdd(&qmass[bin], q);
        }
    }
    #pragma unroll
    for (int o = 32; o > 0; o >>= 1) mloc = fmaxf(mloc, __shfl_down(mloc, o, 64));
    if ((tid & 63) == 0) wred[tid >> 6] = mloc;
    __syncthreads();
    if (tid < 16) {
        float vv = wred[tid];
        #pragma unroll
        for (int o = 8; o > 0; o >>= 1) vv = fmaxf(vv, __shfl_down(vv, o, 16));
        if (tid == 0) sh_m = vv;
    }
    __syncthreads();
    const float m = sh_m;

    const int b0 = tid * NCH;
    float chs = 0.0f;
    #pragma unroll
    for (int i2 = 0; i2 < NCH; ++i2) {
        int b = b0 + i2;
        if (b < NBIN) chs += qmass[b];
    }
    ct[tid] = chs;
    __syncthreads();
    float* src = ct; float* dst = ct2;
    for (int d = 1; d < ONT; d <<= 1) {
        float val = src[tid] + ((tid + d < ONT) ? src[tid + d] : 0.0f);
        dst[tid] = val;
        __syncthreads();
        float* tm = src; src = dst; dst = tm;
    }
    const float Zq = src[0];
    const float P = topp * Zq;
    {
        float mine = src[tid];
        float nxt = (tid + 1 < ONT) ? src[tid + 1] : 0.0f;
        if (mine > P && nxt <= P)
            atomicMax(&sh_cross, ((unsigned long long)(tid + 1) << 32));
    }
    __syncthreads();
    if (tid == 0) {
        sh_Zq = Zq;
        if (sh_cross == 0ull) { sh_bstar = -1000000; sh_A = 0.0f; }
        else {
            int cstar = (int)(sh_cross >> 32) - 1;
            float run = (cstar + 1 < ONT) ? src[cstar + 1] : 0.0f;
            int bst = -1; float abv = run;
            for (int i2 = NCH - 1; i2 >= 0; --i2) {
                int b = cstar * NCH + i2;
                if (b >= NBIN) continue;
                float inc = qmass[b];
                if (run <= P && run + inc > P) { bst = b; abv = run; break; }
                run += inc;
            }
            if (bst < 0) { bst = cstar * NCH; abv = run; }
            sh_bstar = bst;
            float A = abv;
            if (bst + 1 < NBIN) A -= qmass[bst + 1];
            if (A < 0.0f) A = 0.0f;
            sh_A = A;
        }
    }
    __syncthreads();

    const int bstar = sh_bstar;
    const float Zrow = sh_Zq * 1048576.0f * __expf(-m);
    const float invZrow = 1.0f / Zrow;

    const float4* __restrict__ u4 = (const float4*)urow;
    unsigned long long mybest = 0ull;
    for (int v = tid; v < NV4; v += ONT) {
        float4 x = l4[v];
        float4 uu = u4[v];
        float xs[4] = {x.x, x.y, x.z, x.w};
        float us[4] = {uu.x, uu.y, uu.z, uu.w};
        #pragma unroll
        for (int c = 0; c < 4; ++c) {
            float s = xs[c] * invT;
            float t = fminf(fmaxf(s + 64.0f, 44.0f), 84.0f);
            int bin = (int)((__float_as_uint(t) - BLO) >> BSH);
            bin = min(bin, NBIN - 1);
            if (bin >= bstar + 2) {
                float e = __expf(s - m);
                float noise = fmaxf(-__logf(us[c]), 1e-10f);
                float r = __fdividef(e * invZrow, noise);
                int i = v * 4 + c;
                unsigned long long key = ((unsigned long long)__float_as_uint(r) << 32)
                                       | (unsigned long long)(0xFFFFFFFFu - (unsigned)i);
                if (key > mybest) mybest = key;
            } else if (bin >= bstar - 1) {
                float e = __expf(s - m);
                float p = e / Zrow;
                int i = v * 4 + c;
                unsigned int pos = atomicAdd(&gcnt, 1u);
                if (pos < GCAP)
                    gkeys[pos] = ((unsigned long long)__float_as_uint(p) << 32)
                               | (unsigned long long)(0xFFFFFFFFu - (unsigned)i);
            }
        }
    }
    atomicMax(&sh_best, mybest);
    __syncthreads();

    unsigned int ngu = gcnt; if (ngu > GCAP) ngu = GCAP;
    const int ng = (int)ngu;
    for (int i = tid; i < GCAP; i += ONT) if (i >= ng) gkeys[i] = 0ull;
    __syncthreads();
    if (ng > 0) {
        for (int k = 2; k <= GCAP; k <<= 1) {
            for (int j = k >> 1; j > 0; j >>= 1) {
                for (int i = tid; i < GCAP; i += ONT) {
                    int ixj = i ^ j;
                    if (ixj > i) {
                        unsigned long long a = gkeys[i], b = gkeys[ixj];
                        bool up = ((i & k) == 0);
                        bool sw = up ? (a < b) : (a > b);
                        if (sw) { gkeys[i] = b; gkeys[ixj] = a; }
                    }
                }
                __syncthreads();
            }
        }
        for (int i = tid; i < GCAP; i += ONT)
            sa[i] = __uint_as_float((unsigned)(gkeys[i] >> 32));
        __syncthreads();
        float* ssrc = sa; float* sdst = sb;
        for (int d = 1; d < GCAP; d <<= 1) {
            for (int i = tid; i < GCAP; i += ONT)
                sdst[i] = ssrc[i] + ((i >= d) ? ssrc[i - d] : 0.0f);
            __syncthreads();
            float* tm = ssrc; ssrc = sdst; sdst = tm;
        }
        const float A_p = sh_A / sh_Zq;
        for (int i = tid; i < GCAP; i += ONT) {
            if (i < ng) {
                float excl = (i == 0) ? A_p : (A_p + ssrc[i - 1]);
                if (excl <= topp) atomicMax(&sh_kstar, i + 1);
            }
        }
        __syncthreads();
        const int kst = sh_kstar;
        unsigned long long gb = 0ull;
        for (int i = tid; i < kst; i += ONT) {
            unsigned long long key = gkeys[i];
            unsigned int idx = 0xFFFFFFFFu - (unsigned)(key & 0xFFFFFFFFull);
            float p = __uint_as_float((unsigned)(key >> 32));
            float u = urow[idx];
            float noise = fmaxf(-__logf(u), 1e-10f);
            float r = __fdividef(p, noise);
            unsigned long long k2 = ((unsigned long long)__float_as_uint(r) << 32)
                                  | (unsigned long long)(0xFFFFFFFFu - idx);
            if (k2 > gb) gb = k2;
        }
        atomicMax(&sh_best, gb);
        __syncthreads();
    }
    if (tid == 0) {
        unsigned long long kk = sh_best;
        out[row] = (int)(0xFFFFFFFFu - (unsigned)(kk & 0xFFFFFFFFull));
    }
}

extern "C" void kernel_launch(void* const* d_in, const int* in_sizes, int n_in,
                              void* d_out, int out_size, void* d_ws, size_t ws_size,
                              hipStream_t stream) {
    const float* logits = (const float*)d_in[0];
    const float* temps  = (const float*)d_in[1];
    const float* topps  = (const float*)d_in[2];
    const float* unoise = (const float*)d_in[3];
    int* out = (int*)d_out;

    if (ws_size < WS_NEEDED) {
        hipLaunchKernelGGL(sampler_fallback, dim3(NROW), dim3(ONT), 0, stream,
                           logits, temps, topps, unoise, out);
        return;
    }

    char* ws = (char*)d_ws;
    float* hist = (float*)(ws + WS_HIST);
    unsigned int* gcnt = (unsigned int*)(ws + WS_GCNT);
    unsigned long long* best = (unsigned long long*)(ws + WS_BEST);
    RowParams* params = (RowParams*)(ws + WS_PARAMS);
    unsigned long long* gather = (unsigned long long*)(ws + WS_GATHER);

    hipMemsetAsync(ws, 0, MEMSET_BYTES, stream);
    hipLaunchKernelGGL(k1_hist, dim3(NROW * SLICES), dim3(TPB1), 0, stream,
                       logits, temps, hist);
    hipLaunchKernelGGL(k2_scan, dim3(NROW), dim3(TPB2), 0, stream,
                       hist, topps, params);
    hipLaunchKernelGGL(k3_race, dim3(NROW * SLICES), dim3(TPB1), 0, stream,
                       logits, temps, unoise, params, best, gcnt, gather);
    hipLaunchKernelGGL(k4_final, dim3(NROW), dim3(TPB2), 0, stream,
                       logits, temps, unoise, params, best, gcnt, gather, out);
}

// Round 3
// 263.261 us; speedup vs baseline: 1.3055x; 1.3055x over previous
//
#include <hip/hip_runtime.h>
#include <stdint.h>

#define NROW 256
#define NV   128000
#define NV4  (NV / 4)
#define NBIN 7680
#define NCH  8
#define BLO  0x42300000u     // bits of 44.0f
#define BSH  10
#define GCAP 4096
#define LOG2E 1.44269504088896340736f
#define SLICES 4
#define TPBH 512             // k1 / k3 block size
#define TPB2 1024
#define LCAP 2048            // k3 LDS staging capacity
#define SLICE_F4 (NV4 / SLICES)   // 8000

#define T_HI_BITS 0x42A7FFFFu     // ~83.99999 -> bin <= 7679

// ---- workspace layout (bytes) ----
#define WS_HIST   0
#define HIST_BYTES ((size_t)NROW * NBIN * 4)                 // 7,864,320
#define WS_GCNT   (HIST_BYTES)                               // 256*32*4 (padded, 128B/row)
#define WS_BEST   (WS_GCNT + (size_t)NROW * 32 * 4)          // 256*8
#define WS_PARAMS (WS_BEST + NROW * 8)                       // 256*16
#define WS_GATHER (WS_PARAMS + NROW * 16)                    // 256*GCAP*8
#define WS_NEEDED (WS_GATHER + (size_t)NROW * GCAP * 8)
#define MEMSET_BYTES (WS_PARAMS)                             // hist + gcnt + best

struct RowParams { int bstar; float A; float P; int pad; };

// monotone race key: log2(p/noise) + const = s*log2e - log2(-log2 u) + const
__device__ __forceinline__ unsigned long long race_key(float s, float u, unsigned idx) {
    float nl  = -__builtin_amdgcn_logf(u);       // -log2(u) > 0
    float l2n = __builtin_amdgcn_logf(nl);       // log2(-log2 u)
    float keyf = fmaf(s, LOG2E, -l2n);
    unsigned kb = __float_as_uint(keyf);
    kb ^= ((unsigned)((int)kb >> 31)) | 0x80000000u;   // ordered-float transform
    return ((unsigned long long)kb << 32) | (unsigned)(~idx);
}

__device__ __forceinline__ int bin_of(float s) {
    float tc = fminf(fmaxf(s + 64.0f, 44.0f), __uint_as_float(T_HI_BITS));
    return (int)((__float_as_uint(tc) - BLO) >> BSH);
}

__device__ __forceinline__ void histo4(float4 x, bool valid, float invT, float* lh) {
    float xs[4] = {x.x, x.y, x.z, x.w};
    #pragma unroll
    for (int c = 0; c < 4; ++c) {
        float s = xs[c] * invT;
        int bin = bin_of(s);
        float q = __builtin_amdgcn_exp2f(fmaf(s, LOG2E, -20.0f)); // exp(s)*2^-20
        if (valid)
            __hip_atomic_fetch_add(&lh[bin], q, __ATOMIC_RELAXED,
                                   __HIP_MEMORY_SCOPE_WORKGROUP);
    }
}

// ---------------- K1: per-slice LDS histogram -> native-atomic merge ---------
__global__ __launch_bounds__(TPBH)
void k1_hist(const float* __restrict__ logits, const float* __restrict__ temps,
             float* __restrict__ hist)
{
    __shared__ float lh[NBIN];
    const int row = blockIdx.x >> 2;
    const int sl  = blockIdx.x & 3;
    for (int b = threadIdx.x; b < NBIN; b += TPBH) lh[b] = 0.0f;
    __syncthreads();
    const float invT = 1.0f / temps[row];
    const float4* __restrict__ l4 =
        (const float4*)(logits + (size_t)row * NV) + sl * SLICE_F4;
    for (int v = threadIdx.x; v < SLICE_F4; v += 4 * TPBH) {
        int i1 = v + TPBH, i2 = v + 2 * TPBH, i3 = v + 3 * TPBH;
        bool g1 = i1 < SLICE_F4, g2 = i2 < SLICE_F4, g3 = i3 < SLICE_F4;
        float4 x0 = l4[v];
        float4 x1 = l4[g1 ? i1 : v];
        float4 x2 = l4[g2 ? i2 : v];
        float4 x3 = l4[g3 ? i3 : v];
        histo4(x0, true, invT, lh);
        histo4(x1, g1, invT, lh);
        histo4(x2, g2, invT, lh);
        histo4(x3, g3, invT, lh);
    }
    __syncthreads();
    float* __restrict__ gh = hist + (size_t)row * NBIN;
    for (int b = threadIdx.x; b < NBIN; b += TPBH) {
        float v = lh[b];
        if (v != 0.0f)
            __hip_atomic_fetch_add(&gh[b], v, __ATOMIC_RELAXED,
                                   __HIP_MEMORY_SCOPE_AGENT);
    }
}

// ---------------- K2: per-row suffix scan -> bstar, A, P ---------------------
__global__ __launch_bounds__(TPB2)
void k2_scan(const float* __restrict__ hist, const float* __restrict__ topps,
             RowParams* __restrict__ params)
{
    __shared__ float qm[NBIN];
    __shared__ float ct[TPB2];
    __shared__ float ct2[TPB2];
    __shared__ unsigned long long sh_cross;
    const int row = blockIdx.x, tid = threadIdx.x;
    const float* __restrict__ gh = hist + (size_t)row * NBIN;
    for (int b = tid; b < NBIN; b += TPB2) qm[b] = gh[b];
    if (tid == 0) sh_cross = 0ull;
    __syncthreads();

    const int b0 = tid * NCH;
    float chs = 0.0f;
    #pragma unroll
    for (int i2 = 0; i2 < NCH; ++i2) {
        int b = b0 + i2;
        if (b < NBIN) chs += qm[b];
    }
    ct[tid] = chs;
    __syncthreads();
    float* src = ct; float* dst = ct2;
    for (int d = 1; d < TPB2; d <<= 1) {       // suffix-inclusive scan
        float val = src[tid] + ((tid + d < TPB2) ? src[tid + d] : 0.0f);
        dst[tid] = val;
        __syncthreads();
        float* tm = src; src = dst; dst = tm;
    }
    const float Zq = src[0];
    const float P = topps[row] * Zq;
    {
        float mine = src[tid];
        float nxt = (tid + 1 < TPB2) ? src[tid + 1] : 0.0f;
        if (mine > P && nxt <= P)
            atomicMax(&sh_cross, ((unsigned long long)(tid + 1) << 32));
    }
    __syncthreads();
    if (tid == 0) {
        RowParams rp; rp.pad = 0; rp.P = P;
        if (sh_cross == 0ull) {
            rp.bstar = -1000000; rp.A = 0.0f;      // keep everything
        } else {
            int cstar = (int)(sh_cross >> 32) - 1;
            float run = (cstar + 1 < TPB2) ? src[cstar + 1] : 0.0f;
            int bst = -1; float abv = run;
            for (int i2 = NCH - 1; i2 >= 0; --i2) {
                int b = cstar * NCH + i2;
                if (b >= NBIN) continue;
                float inc = qm[b];
                if (run <= P && run + inc > P) { bst = b; abv = run; break; }
                run += inc;
            }
            if (bst < 0) { bst = cstar * NCH; abv = run; }
            rp.bstar = bst;
            rp.A = abv;                            // mass of bins >= bstar+1
        }
        params[row] = rp;
    }
}

// ---------------- K3: per-slice race over kept + staged boundary gather ------
__global__ __launch_bounds__(TPBH)
void k3_race(const float* __restrict__ logits, const float* __restrict__ temps,
             const float* __restrict__ unoise, const RowParams* __restrict__ params,
             unsigned long long* __restrict__ best, unsigned int* __restrict__ gcnt,
             unsigned long long* __restrict__ gather)
{
    __shared__ unsigned long long stage[LCAP];
    __shared__ unsigned long long wb[TPBH / 64];
    __shared__ unsigned int lcnt;
    __shared__ unsigned int sh_base;
    const int row = blockIdx.x >> 2;
    const int sl  = blockIdx.x & 3;
    const int tid = threadIdx.x;
    if (tid == 0) lcnt = 0u;
    __syncthreads();
    const RowParams rp = params[row];
    const int bstar = rp.bstar;
    const float invT = 1.0f / temps[row];
    const float4* __restrict__ l4 =
        (const float4*)(logits + (size_t)row * NV) + sl * SLICE_F4;
    const float4* __restrict__ u4 =
        (const float4*)(unoise + (size_t)row * NV) + sl * SLICE_F4;
    unsigned long long* __restrict__ grow = gather + (size_t)row * GCAP;
    unsigned int* __restrict__ gcr = &gcnt[row * 32];
    const int ibase = sl * SLICE_F4 * 4;
    unsigned long long mybest = 0ull;

    auto proc4 = [&](float4 x, float4 uu, bool valid, int vidx) {
        float xs[4] = {x.x, x.y, x.z, x.w};
        float us[4] = {uu.x, uu.y, uu.z, uu.w};
        #pragma unroll
        for (int c = 0; c < 4; ++c) {
            float s = xs[c] * invT;
            int bin = bin_of(s);
            unsigned idx = (unsigned)(ibase + vidx * 4 + c);
            if (valid && bin > bstar) {             // definitely in nucleus
                unsigned long long key = race_key(s, us[c], idx);
                if (key > mybest) mybest = key;
            } else if (valid && bin >= bstar - 1) { // boundary bins
                float q = __builtin_amdgcn_exp2f(fmaf(s, LOG2E, -20.0f));
                unsigned long long ent =
                    ((unsigned long long)__float_as_uint(q) << 32) | (unsigned)(~idx);
                unsigned pos = atomicAdd(&lcnt, 1u);
                if (pos < LCAP) stage[pos] = ent;
                else {                               // overflow: direct global
                    unsigned gp = atomicAdd(gcr, 1u);
                    if (gp < GCAP) grow[gp] = ent;
                }
            }
        }
    };

    for (int v = tid; v < SLICE_F4; v += 2 * TPBH) {
        int i1 = v + TPBH;
        bool g1 = i1 < SLICE_F4;
        float4 x0 = l4[v];
        float4 x1 = l4[g1 ? i1 : v];
        float4 u0 = u4[v];
        float4 u1 = u4[g1 ? i1 : v];
        proc4(x0, u0, true, v);
        proc4(x1, u1, g1, i1);
    }

    // block reduction of mybest
    #pragma unroll
    for (int o = 32; o > 0; o >>= 1) {
        unsigned long long other = __shfl_down(mybest, o, 64);
        if (other > mybest) mybest = other;
    }
    if ((tid & 63) == 0) wb[tid >> 6] = mybest;
    __syncthreads();
    if (tid == 0) {
        unsigned long long m2 = wb[0];
        #pragma unroll
        for (int w = 1; w < TPBH / 64; ++w) if (wb[w] > m2) m2 = wb[w];
        if (m2) atomicMax(&best[row], m2);
        unsigned int n = lcnt; if (n > LCAP) n = LCAP;
        sh_base = (n > 0u) ? atomicAdd(gcr, n) : 0xFFFFFFF0u;
    }
    __syncthreads();
    unsigned int n = lcnt; if (n > LCAP) n = LCAP;
    unsigned int base = sh_base;
    for (unsigned int i = tid; i < n; i += TPBH) {
        unsigned int p = base + i;
        if (p < GCAP) grow[p] = stage[i];
    }
}

// ---------------- K4: per-row sort boundary, exact cut, final winner ---------
__global__ __launch_bounds__(TPB2)
void k4_final(const float* __restrict__ logits, const float* __restrict__ temps,
              const float* __restrict__ unoise, const RowParams* __restrict__ params,
              const unsigned long long* __restrict__ best,
              const unsigned int* __restrict__ gcnt,
              const unsigned long long* __restrict__ gather, int* __restrict__ out)
{
    __shared__ unsigned long long gk[GCAP];
    __shared__ float sa[GCAP];
    __shared__ float sb[GCAP];
    __shared__ int sh_kst;
    __shared__ unsigned long long sh_best;
    const int row = blockIdx.x, tid = threadIdx.x;
    const RowParams rp = params[row];
    unsigned int ngu = gcnt[row * 32];
    if (ngu > GCAP) ngu = GCAP;
    const int ng = (int)ngu;
    if (tid == 0) { sh_kst = 0; sh_best = best[row]; }
    if (ng > 0) {
        int N2 = 64; while (N2 < ng) N2 <<= 1;
        const unsigned long long* __restrict__ grow = gather + (size_t)row * GCAP;
        for (int i = tid; i < N2; i += TPB2) gk[i] = (i < ng) ? grow[i] : 0ull;
        __syncthreads();
        for (int k = 2; k <= N2; k <<= 1) {
            for (int j = k >> 1; j > 0; j >>= 1) {
                for (int i = tid; i < N2; i += TPB2) {
                    int ixj = i ^ j;
                    if (ixj > i) {
                        unsigned long long a = gk[i], b = gk[ixj];
                        bool up = ((i & k) == 0);
                        if (up ? (a < b) : (a > b)) { gk[i] = b; gk[ixj] = a; }
                    }
                }
                __syncthreads();
            }
        }
        for (int i = tid; i < N2; i += TPB2)
            sa[i] = __uint_as_float((unsigned)(gk[i] >> 32));
        __syncthreads();
        float* ssrc = sa; float* sdst = sb;
        for (int d = 1; d < N2; d <<= 1) {
            for (int i = tid; i < N2; i += TPB2)
                sdst[i] = ssrc[i] + ((i >= d) ? ssrc[i - d] : 0.0f);
            __syncthreads();
            float* tm = ssrc; ssrc = sdst; sdst = tm;
        }
        for (int i = tid; i < ng; i += TPB2) {
            float excl = rp.A + ((i == 0) ? 0.0f : ssrc[i - 1]);
            if (excl <= rp.P) atomicMax(&sh_kst, i + 1);
        }
        __syncthreads();
        const int kst = sh_kst;
        const float* __restrict__ lrow = logits + (size_t)row * NV;
        const float* __restrict__ urow = unoise + (size_t)row * NV;
        const float invT = 1.0f / temps[row];
        unsigned long long gb = 0ull;
        for (int i = tid; i < kst; i += TPB2) {
            unsigned idx = ~(unsigned)(gk[i] & 0xFFFFFFFFull);
            float s = lrow[idx] * invT;
            unsigned long long key = race_key(s, urow[idx], idx);
            if (key > gb) gb = key;
        }
        #pragma unroll
        for (int o = 32; o > 0; o >>= 1) {
            unsigned long long other = __shfl_down(gb, o, 64);
            if (other > gb) gb = other;
        }
        if ((tid & 63) == 0 && gb) atomicMax(&sh_best, gb);
        __syncthreads();
    }
    if (tid == 0) out[row] = (int)(~(unsigned)(sh_best & 0xFFFFFFFFull));
}

// =================== fallback: proven round-1 single kernel ==================
#define ONT 1024
__global__ __launch_bounds__(ONT, 1)
void sampler_fallback(const float* __restrict__ logits,
                      const float* __restrict__ temps,
                      const float* __restrict__ topps,
                      const float* __restrict__ unoise,
                      int* __restrict__ out)
{
    __shared__ float qmass[NBIN];
    __shared__ float ct[ONT];
    __shared__ float ct2[ONT];
    __shared__ unsigned long long gkeys[GCAP];
    __shared__ float sa[GCAP];
    __shared__ float sb[GCAP];
    __shared__ float wred[16];
    __shared__ unsigned long long sh_cross;
    __shared__ unsigned long long sh_best;
    __shared__ unsigned int gcnt;
    __shared__ int sh_bstar;
    __shared__ float sh_A;
    __shared__ float sh_m;
    __shared__ float sh_Zq;
    __shared__ int sh_kstar;

    const int row = blockIdx.x;
    const int tid = threadIdx.x;
    const float* __restrict__ lrow = logits + (size_t)row * NV;
    const float* __restrict__ urow = unoise + (size_t)row * NV;
    const float invT = 1.0f / temps[row];
    const float topp = topps[row];

    for (int b = tid; b < NBIN; b += ONT) qmass[b] = 0.0f;
    if (tid == 0) { sh_cross = 0ull; sh_best = 0ull; gcnt = 0u; sh_kstar = 0; sh_bstar = 0; sh_A = 0.0f; }
    __syncthreads();

    const float4* __restrict__ l4 = (const float4*)lrow;
    float mloc = -3.402823466e38f;
    const float qscale = 9.5367431640625e-07f;
    for (int v = tid; v < NV4; v += ONT) {
        float4 x = l4[v];
        float xs[4] = {x.x, x.y, x.z, x.w};
        #pragma unroll
        for (int c = 0; c < 4; ++c) {
            float s = xs[c] * invT;
            mloc = fmaxf(mloc, s);
            float q = __expf(s) * qscale;
            float t = fminf(fmaxf(s + 64.0f, 44.0f), 84.0f);
            int bin = (int)((__float_as_uint(t) - BLO) >> BSH);
            bin = min(bin, NBIN - 1);
            atomicAdd(&qmass[bin], q);
        }
    }
    #pragma unroll
    for (int o = 32; o > 0; o >>= 1) mloc = fmaxf(mloc, __shfl_down(mloc, o, 64));
    if ((tid & 63) == 0) wred[tid >> 6] = mloc;
    __syncthreads();
    if (tid < 16) {
        float vv = wred[tid];
        #pragma unroll
        for (int o = 8; o > 0; o >>= 1) vv = fmaxf(vv, __shfl_down(vv, o, 16));
        if (tid == 0) sh_m = vv;
    }
    __syncthreads();
    const float m = sh_m;

    const int b0 = tid * NCH;
    float chs = 0.0f;
    #pragma unroll
    for (int i2 = 0; i2 < NCH; ++i2) {
        int b = b0 + i2;
        if (b < NBIN) chs += qmass[b];
    }
    ct[tid] = chs;
    __syncthreads();
    float* src = ct; float* dst = ct2;
    for (int d = 1; d < ONT; d <<= 1) {
        float val = src[tid] + ((tid + d < ONT) ? src[tid + d] : 0.0f);
        dst[tid] = val;
        __syncthreads();
        float* tm = src; src = dst; dst = tm;
    }
    const float Zq = src[0];
    const float P = topp * Zq;
    {
        float mine = src[tid];
        float nxt = (tid + 1 < ONT) ? src[tid + 1] : 0.0f;
        if (mine > P && nxt <= P)
            atomicMax(&sh_cross, ((unsigned long long)(tid + 1) << 32));
    }
    __syncthreads();
    if (tid == 0) {
        sh_Zq = Zq;
        if (sh_cross == 0ull) { sh_bstar = -1000000; sh_A = 0.0f; }
        else {
            int cstar = (int)(sh_cross >> 32) - 1;
            float run = (cstar + 1 < ONT) ? src[cstar + 1] : 0.0f;
            int bst = -1; float abv = run;
            for (int i2 = NCH - 1; i2 >= 0; --i2) {
                int b = cstar * NCH + i2;
                if (b >= NBIN) continue;
                float inc = qmass[b];
                if (run <= P && run + inc > P) { bst = b; abv = run; break; }
                run += inc;
            }
            if (bst < 0) { bst = cstar * NCH; abv = run; }
            sh_bstar = bst;
            float A = abv;
            if (bst + 1 < NBIN) A -= qmass[bst + 1];
            if (A < 0.0f) A = 0.0f;
            sh_A = A;
        }
    }
    __syncthreads();

    const int bstar = sh_bstar;
    const float Zrow = sh_Zq * 1048576.0f * __expf(-m);
    const float invZrow = 1.0f / Zrow;

    const float4* __restrict__ u4 = (const float4*)urow;
    unsigned long long mybest = 0ull;
    for (int v = tid; v < NV4; v += ONT) {
        float4 x = l4[v];
        float4 uu = u4[v];
        float xs[4] = {x.x, x.y, x.z, x.w};
        float us[4] = {uu.x, uu.y, uu.z, uu.w};
        #pragma unroll
        for (int c = 0; c < 4; ++c) {
            float s = xs[c] * invT;
            float t = fminf(fmaxf(s + 64.0f, 44.0f), 84.0f);
            int bin = (int)((__float_as_uint(t) - BLO) >> BSH);
            bin = min(bin, NBIN - 1);
            if (bin >= bstar + 2) {
                float e = __expf(s - m);
                float noise = fmaxf(-__logf(us[c]), 1e-10f);
                float r = __fdividef(e * invZrow, noise);
                int i = v * 4 + c;
                unsigned long long key = ((unsigned long long)__float_as_uint(r) << 32)
                                       | (unsigned long long)(0xFFFFFFFFu - (unsigned)i);
                if (key > mybest) mybest = key;
            } else if (bin >= bstar - 1) {
                float e = __expf(s - m);
                float p = e / Zrow;
                int i = v * 4 + c;
                unsigned int pos = atomicAdd(&gcnt, 1u);
                if (pos < GCAP)
                    gkeys[pos] = ((unsigned long long)__float_as_uint(p) << 32)
                               | (unsigned long long)(0xFFFFFFFFu - (unsigned)i);
            }
        }
    }
    atomicMax(&sh_best, mybest);
    __syncthreads();

    unsigned int ngu = gcnt; if (ngu > GCAP) ngu = GCAP;
    const int ng = (int)ngu;
    for (int i = tid; i < GCAP; i += ONT) if (i >= ng) gkeys[i] = 0ull;
    __syncthreads();
    if (ng > 0) {
        for (int k = 2; k <= GCAP; k <<= 1) {
            for (int j = k >> 1; j > 0; j >>= 1) {
                for (int i = tid; i < GCAP; i += ONT) {
                    int ixj = i ^ j;
                    if (ixj > i) {
                        unsigned long long a = gkeys[i], b = gkeys[ixj];
                        bool up = ((i & k) == 0);
                        bool sw = up ? (a < b) : (a > b);
                        if (sw) { gkeys[i] = b; gkeys[ixj] = a; }
                    }
                }
                __syncthreads();
            }
        }
        for (int i = tid; i < GCAP; i += ONT)
            sa[i] = __uint_as_float((unsigned)(gkeys[i] >> 32));
        __syncthreads();
        float* ssrc = sa; float* sdst = sb;
        for (int d = 1; d < GCAP; d <<= 1) {
            for (int i = tid; i < GCAP; i += ONT)
                sdst[i] = ssrc[i] + ((i >= d) ? ssrc[i - d] : 0.0f);
            __syncthreads();
            float* tm = ssrc; ssrc = sdst; sdst = tm;
        }
        const float A_p = sh_A / sh_Zq;
        for (int i = tid; i < GCAP; i += ONT) {
            if (i < ng) {
                float excl = (i == 0) ? A_p : (A_p + ssrc[i - 1]);
                if (excl <= topp) atomicMax(&sh_kstar, i + 1);
            }
        }
        __syncthreads();
        const int kst = sh_kstar;
        unsigned long long gb = 0ull;
        for (int i = tid; i < kst; i += ONT) {
            unsigned long long key = gkeys[i];
            unsigned int idx = 0xFFFFFFFFu - (unsigned)(key & 0xFFFFFFFFull);
            float p = __uint_as_float((unsigned)(key >> 32));
            float u = urow[idx];
            float noise = fmaxf(-__logf(u), 1e-10f);
            float r = __fdividef(p, noise);
            unsigned long long k2 = ((unsigned long long)__float_as_uint(r) << 32)
                                  | (unsigned long long)(0xFFFFFFFFu - idx);
            if (k2 > gb) gb = k2;
        }
        atomicMax(&sh_best, gb);
        __syncthreads();
    }
    if (tid == 0) {
        unsigned long long kk = sh_best;
        out[row] = (int)(0xFFFFFFFFu - (unsigned)(kk & 0xFFFFFFFFull));
    }
}

extern "C" void kernel_launch(void* const* d_in, const int* in_sizes, int n_in,
                              void* d_out, int out_size, void* d_ws, size_t ws_size,
                              hipStream_t stream) {
    const float* logits = (const float*)d_in[0];
    const float* temps  = (const float*)d_in[1];
    const float* topps  = (const float*)d_in[2];
    const float* unoise = (const float*)d_in[3];
    int* out = (int*)d_out;

    if (ws_size < WS_NEEDED) {
        hipLaunchKernelGGL(sampler_fallback, dim3(NROW), dim3(ONT), 0, stream,
                           logits, temps, topps, unoise, out);
        return;
    }

    char* ws = (char*)d_ws;
    float* hist = (float*)(ws + WS_HIST);
    unsigned int* gcnt = (unsigned int*)(ws + WS_GCNT);
    unsigned long long* best = (unsigned long long*)(ws + WS_BEST);
    RowParams* params = (RowParams*)(ws + WS_PARAMS);
    unsigned long long* gather = (unsigned long long*)(ws + WS_GATHER);

    hipMemsetAsync(ws, 0, MEMSET_BYTES, stream);
    hipLaunchKernelGGL(k1_hist, dim3(NROW * SLICES), dim3(TPBH), 0, stream,
                       logits, temps, hist);
    hipLaunchKernelGGL(k2_scan, dim3(NROW), dim3(TPB2), 0, stream,
                       hist, topps, params);
    hipLaunchKernelGGL(k3_race, dim3(NROW * SLICES), dim3(TPBH), 0, stream,
                       logits, temps, unoise, params, best, gcnt, gather);
    hipLaunchKernelGGL(k4_final, dim3(NROW), dim3(TPB2), 0, stream,
                       logits, temps, unoise, params, best, gcnt, gather, out);
}

// Round 4
// 209.131 us; speedup vs baseline: 1.6434x; 1.2588x over previous
//
#include <hip/hip_runtime.h>
#include <stdint.h>

#define NROW 256
#define NV   128000
#define NV4  (NV / 4)
#define HALF_F4 (NV4 / 2)       // 16000 float4 per half-row
#define NBIN 7680
#define NCH  8
#define BLO  0x42300000u        // bits of 44.0f
#define BSH  10
#define GCAP 4096
#define LOG2E 1.44269504088896340736f
#define TPB  1024
#define LCAP 2048
#define RMARG 1.005f
#define T_HI_BITS 0x42A7FFFFu   // ~83.99999 -> bin <= 7679

// ---- workspace layout (bytes) ----
#define PART_BYTES ((size_t)512 * (NBIN / 2) * 4)        // 7,864,320 (packed u16 pairs)
#define WS_PART   0
#define WS_ZQ     (PART_BYTES)                            // 256*8 f32
#define WS_SAB    (WS_ZQ   + (size_t)NROW * 8 * 4)
#define WS_GCNT   (WS_SAB  + (size_t)NROW * 8 * 4)
#define WS_BEST   (WS_GCNT + (size_t)NROW * 8 * 4)
#define WS_PARAMS (WS_BEST + (size_t)NROW * 8)
#define WS_GATHER (WS_PARAMS + (size_t)NROW * 16)
#define WS_NEEDED (WS_GATHER + (size_t)NROW * GCAP * 8)   // = 16,283,648
#define MEMSET_OFF  WS_ZQ
#define MEMSET_BYTES (WS_GATHER - WS_ZQ)

struct RowParams { int bl; int bh; float P; int pad; };

__device__ __forceinline__ unsigned fenc(float f) {
    unsigned b = __float_as_uint(f);
    return b ^ (((unsigned)((int)b >> 31)) | 0x80000000u);
}
__device__ __forceinline__ float fdec(unsigned e) {
    unsigned m = ((int)e >= 0) ? 0xFFFFFFFFu : 0x80000000u;
    return __uint_as_float(e ^ m);
}

// monotone race key: log2(p/noise) + const = s*log2e - log2(-log2 u) + const
__device__ __forceinline__ unsigned long long race_key(float s, float u, unsigned idx) {
    float nl  = -__builtin_amdgcn_logf(u);
    float l2n = __builtin_amdgcn_logf(nl);
    float keyf = fmaf(s, LOG2E, -l2n);
    return ((unsigned long long)fenc(keyf) << 32) | (unsigned)(~idx);
}

__device__ __forceinline__ int bin_of(float s) {
    float tc = fminf(fmaxf(s + 64.0f, 44.0f), __uint_as_float(T_HI_BITS));
    return (int)((__float_as_uint(tc) - BLO) >> BSH);
}

__device__ __forceinline__ float qval(float s) {       // exp(s) * 2^-20
    return __builtin_amdgcn_exp2f(fmaf(s, LOG2E, -20.0f));
}

__device__ __forceinline__ float cmid(int b) {         // geometric-mid mass of bin b
    float tlo = __uint_as_float(BLO + ((unsigned)b << BSH));
    float thi = __uint_as_float(BLO + ((unsigned)(b + 1) << BSH));
    float tm = 0.5f * (tlo + thi);
    return __builtin_amdgcn_exp2f(fmaf(tm - 64.0f, LOG2E, -20.0f));
}

// ---------------- K1: integer count histogram + exact Zq reduction -----------
__global__ __launch_bounds__(TPB)
void k1_hist(const float* __restrict__ logits, const float* __restrict__ temps,
             unsigned* __restrict__ partials, float* __restrict__ zq)
{
    __shared__ unsigned lh[NBIN];
    __shared__ float wred[16];
    const int row = blockIdx.x >> 1;
    const int sl  = blockIdx.x & 1;
    const int tid = threadIdx.x;
    for (int b = tid; b < NBIN; b += TPB) lh[b] = 0u;
    __syncthreads();
    const float invT = 1.0f / temps[row];
    const float4* __restrict__ l4 =
        (const float4*)(logits + (size_t)row * NV) + sl * HALF_F4;
    float zacc = 0.0f;
    for (int v = tid; v < HALF_F4; v += TPB) {
        float4 x = l4[v];
        float xs[4] = {x.x, x.y, x.z, x.w};
        #pragma unroll
        for (int c = 0; c < 4; ++c) {
            float s = xs[c] * invT;
            atomicAdd(&lh[bin_of(s)], 1u);
            zacc += qval(s);
        }
    }
    #pragma unroll
    for (int o = 32; o > 0; o >>= 1) zacc += __shfl_down(zacc, o, 64);
    if ((tid & 63) == 0) wred[tid >> 6] = zacc;
    __syncthreads();
    if (tid == 0) {
        float z = 0.0f;
        #pragma unroll
        for (int w = 0; w < TPB / 64; ++w) z += wred[w];
        __hip_atomic_fetch_add(&zq[row * 8], z, __ATOMIC_RELAXED,
                               __HIP_MEMORY_SCOPE_AGENT);
    }
    unsigned* __restrict__ pc = partials + (size_t)blockIdx.x * (NBIN / 2);
    for (int pb = tid; pb < NBIN / 2; pb += TPB)
        pc[pb] = (lh[2 * pb] & 0xFFFFu) | (lh[2 * pb + 1] << 16);
}

// ---------------- K2: merge counts, bounded window [bL', bH] -----------------
__global__ __launch_bounds__(TPB)
void k2_scan(const unsigned* __restrict__ partials, const float* __restrict__ topps,
             const float* __restrict__ zq, RowParams* __restrict__ params)
{
    __shared__ float qm[NBIN];    // mass (then per-bin mass suffix)
    __shared__ float qc[NBIN];    // count (then per-bin count suffix)
    __shared__ float ct[TPB];
    __shared__ float ct2[TPB];
    __shared__ int shbH, shbL, shbLp;
    const int row = blockIdx.x, tid = threadIdx.x;
    const unsigned* __restrict__ p0 = partials + (size_t)(row * 2) * (NBIN / 2);
    const unsigned* __restrict__ p1 = p0 + (NBIN / 2);
    for (int pb = tid; pb < NBIN / 2; pb += TPB) {
        unsigned a = p0[pb], b = p1[pb];
        unsigned c0 = (a & 0xFFFFu) + (b & 0xFFFFu);
        unsigned c1 = (a >> 16) + (b >> 16);
        int b0 = 2 * pb, b1 = 2 * pb + 1;
        qc[b0] = (float)c0; qm[b0] = c0 ? (float)c0 * cmid(b0) : 0.0f;
        qc[b1] = (float)c1; qm[b1] = c1 ? (float)c1 * cmid(b1) : 0.0f;
    }
    if (tid == 0) { shbH = NBIN - 1; shbL = 0; }
    __syncthreads();

    // mass: chunk sums -> suffix scan -> per-bin suffix writeback
    float chs = 0.0f;
    if (tid < NBIN / NCH) {
        int b0 = tid * NCH;
        #pragma unroll
        for (int i = 0; i < NCH; ++i) chs += qm[b0 + i];
    }
    ct[tid] = chs;
    __syncthreads();
    float* src = ct; float* dst = ct2;
    for (int d = 1; d < TPB; d <<= 1) {
        float v = src[tid] + ((tid + d < TPB) ? src[tid + d] : 0.0f);
        dst[tid] = v;
        __syncthreads();
        float* tm = src; src = dst; dst = tm;
    }
    {
        float run = (tid + 1 < TPB) ? src[tid + 1] : 0.0f;
        if (tid < NBIN / NCH) {
            int b0 = tid * NCH;
            for (int i = NCH - 1; i >= 0; --i) { run += qm[b0 + i]; qm[b0 + i] = run; }
        }
    }
    __syncthreads();

    // counts: same machinery
    float chc = 0.0f;
    if (tid < NBIN / NCH) {
        int b0 = tid * NCH;
        #pragma unroll
        for (int i = 0; i < NCH; ++i) chc += qc[b0 + i];
    }
    ct[tid] = chc;
    __syncthreads();
    src = ct; dst = ct2;
    for (int d = 1; d < TPB; d <<= 1) {
        float v = src[tid] + ((tid + d < TPB) ? src[tid + d] : 0.0f);
        dst[tid] = v;
        __syncthreads();
        float* tm = src; src = dst; dst = tm;
    }
    {
        float run = (tid + 1 < TPB) ? src[tid + 1] : 0.0f;
        if (tid < NBIN / NCH) {
            int b0 = tid * NCH;
            for (int i = NCH - 1; i >= 0; --i) { run += qc[b0 + i]; qc[b0 + i] = run; }
        }
    }
    __syncthreads();

    const float P = topps[row] * zq[row * 8];
    if (tid < NBIN / NCH) {
        int b0 = tid * NCH;
        for (int i = 0; i < NCH; ++i) {
            int b = b0 + i;
            float Sb  = qm[b];
            float Sb1 = (b + 1 < NBIN) ? qm[b + 1] : 0.0f;
            if (Sb1 * RMARG <= P) atomicMin(&shbH, b);   // bins > bH definitely kept
            if (Sb > RMARG * P)   atomicMax(&shbL, b);   // bins < bL definitely masked
        }
    }
    __syncthreads();
    const int bH = shbH;
    if (tid == 0) shbLp = bH;
    __syncthreads();
    const float target = (float)GCAP + ((bH + 1 < NBIN) ? qc[bH + 1] : 0.0f);
    const int bL = shbL;
    if (tid < NBIN / NCH) {
        int b0 = tid * NCH;
        for (int i = 0; i < NCH; ++i) {
            int b = b0 + i;
            if (b >= bL && qc[b] <= target) atomicMin(&shbLp, b);  // fit in GCAP
        }
    }
    __syncthreads();
    if (tid == 0) {
        RowParams rp; rp.bl = shbLp; rp.bh = bH; rp.P = P; rp.pad = 0;
        params[row] = rp;
    }
}

// ---------------- K3: race over kept, gather window, exact S_above -----------
__global__ __launch_bounds__(TPB)
void k3_race(const float* __restrict__ logits, const float* __restrict__ temps,
             const float* __restrict__ unoise, const RowParams* __restrict__ params,
             unsigned long long* __restrict__ best, unsigned int* __restrict__ gcnt,
             unsigned long long* __restrict__ gather, float* __restrict__ sab)
{
    __shared__ unsigned long long stage[LCAP];
    __shared__ unsigned long long wb[16];
    __shared__ float wsab[16];
    __shared__ unsigned int lcnt;
    __shared__ unsigned int sh_base;
    const int row = blockIdx.x >> 1;
    const int sl  = blockIdx.x & 1;
    const int tid = threadIdx.x;
    if (tid == 0) lcnt = 0u;
    __syncthreads();
    const RowParams rp = params[row];
    const int bl = rp.bl, bh = rp.bh;
    const float invT = 1.0f / temps[row];
    const float4* __restrict__ l4 =
        (const float4*)(logits + (size_t)row * NV) + sl * HALF_F4;
    const float4* __restrict__ u4 =
        (const float4*)(unoise + (size_t)row * NV) + sl * HALF_F4;
    unsigned long long* __restrict__ grow = gather + (size_t)row * GCAP;
    unsigned int* __restrict__ gcr = &gcnt[row * 8];
    const int ibase = sl * HALF_F4 * 4;
    unsigned long long mybest = 0ull;
    float sabacc = 0.0f;

    for (int v = tid; v < HALF_F4; v += TPB) {
        float4 x = l4[v];
        float4 uu = u4[v];
        float xs[4] = {x.x, x.y, x.z, x.w};
        float us[4] = {uu.x, uu.y, uu.z, uu.w};
        #pragma unroll
        for (int c = 0; c < 4; ++c) {
            float s = xs[c] * invT;
            int bin = bin_of(s);
            unsigned idx = (unsigned)(ibase + v * 4 + c);
            if (bin > bh) {                       // definitely in nucleus
                unsigned long long key = race_key(s, us[c], idx);
                if (key > mybest) mybest = key;
                sabacc += qval(s);
            } else if (bin >= bl) {               // uncertainty window
                unsigned long long ent =
                    ((unsigned long long)fenc(s) << 32) | (unsigned)(~idx);
                unsigned pos = atomicAdd(&lcnt, 1u);
                if (pos < LCAP) stage[pos] = ent;
                else {
                    unsigned gp = atomicAdd(gcr, 1u);
                    if (gp < GCAP) grow[gp] = ent;
                }
            }
        }
    }
    #pragma unroll
    for (int o = 32; o > 0; o >>= 1) {
        unsigned long long other = __shfl_down(mybest, o, 64);
        if (other > mybest) mybest = other;
        sabacc += __shfl_down(sabacc, o, 64);
    }
    if ((tid & 63) == 0) { wb[tid >> 6] = mybest; wsab[tid >> 6] = sabacc; }
    __syncthreads();
    if (tid == 0) {
        unsigned long long m2 = wb[0];
        float sz = wsab[0];
        #pragma unroll
        for (int w = 1; w < TPB / 64; ++w) {
            if (wb[w] > m2) m2 = wb[w];
            sz += wsab[w];
        }
        if (m2) atomicMax(&best[row], m2);
        __hip_atomic_fetch_add(&sab[row * 8], sz, __ATOMIC_RELAXED,
                               __HIP_MEMORY_SCOPE_AGENT);
        unsigned int n = lcnt; if (n > LCAP) n = LCAP;
        sh_base = (n > 0u) ? atomicAdd(gcr, n) : 0xFFFFFFF0u;
    }
    __syncthreads();
    unsigned int n = lcnt; if (n > LCAP) n = LCAP;
    unsigned int base = sh_base;
    for (unsigned int i = tid; i < n; i += TPB) {
        unsigned int p = base + i;
        if (p < GCAP) grow[p] = stage[i];
    }
}

// ---------------- K4: sort window, exact cut, final winner -------------------
__global__ __launch_bounds__(TPB)
void k4_final(const float* __restrict__ unoise, const RowParams* __restrict__ params,
              const unsigned long long* __restrict__ best,
              const unsigned int* __restrict__ gcnt,
              const unsigned long long* __restrict__ gather,
              const float* __restrict__ sab, int* __restrict__ out)
{
    __shared__ unsigned long long gk[GCAP];
    __shared__ float sa[GCAP];
    __shared__ float sb[GCAP];
    __shared__ int sh_kst;
    __shared__ unsigned long long sh_best;
    const int row = blockIdx.x, tid = threadIdx.x;
    const RowParams rp = params[row];
    unsigned int ngu = gcnt[row * 8];
    if (ngu > GCAP) ngu = GCAP;
    const int ng = (int)ngu;
    if (tid == 0) { sh_kst = 0; sh_best = best[row]; }
    if (ng > 0) {
        int N2 = 64; while (N2 < ng) N2 <<= 1;
        const unsigned long long* __restrict__ grow = gather + (size_t)row * GCAP;
        for (int i = tid; i < N2; i += TPB) gk[i] = (i < ng) ? grow[i] : 0ull;
        __syncthreads();
        for (int k = 2; k <= N2; k <<= 1) {
            for (int j = k >> 1; j > 0; j >>= 1) {
                for (int i = tid; i < N2; i += TPB) {
                    int ixj = i ^ j;
                    if (ixj > i) {
                        unsigned long long a = gk[i], b = gk[ixj];
                        bool up = ((i & k) == 0);
                        if (up ? (a < b) : (a > b)) { gk[i] = b; gk[ixj] = a; }
                    }
                }
                __syncthreads();
            }
        }
        for (int i = tid; i < N2; i += TPB)
            sa[i] = (i < ng) ? qval(fdec((unsigned)(gk[i] >> 32))) : 0.0f;
        __syncthreads();
        float* ssrc = sa; float* sdst = sb;
        for (int d = 1; d < N2; d <<= 1) {
            for (int i = tid; i < N2; i += TPB)
                sdst[i] = ssrc[i] + ((i >= d) ? ssrc[i - d] : 0.0f);
            __syncthreads();
            float* tm = ssrc; ssrc = sdst; sdst = tm;
        }
        const float A = sab[row * 8];
        for (int i = tid; i < ng; i += TPB) {
            float excl = A + ((i == 0) ? 0.0f : ssrc[i - 1]);
            if (excl <= rp.P) atomicMax(&sh_kst, i + 1);
        }
        __syncthreads();
        const int kst = sh_kst;
        const float* __restrict__ urow = unoise + (size_t)row * NV;
        unsigned long long gb = 0ull;
        for (int i = tid; i < kst; i += TPB) {
            unsigned idx = ~(unsigned)(gk[i] & 0xFFFFFFFFull);
            float s = fdec((unsigned)(gk[i] >> 32));
            unsigned long long key = race_key(s, urow[idx], idx);
            if (key > gb) gb = key;
        }
        #pragma unroll
        for (int o = 32; o > 0; o >>= 1) {
            unsigned long long other = __shfl_down(gb, o, 64);
            if (other > gb) gb = other;
        }
        if ((tid & 63) == 0 && gb) atomicMax(&sh_best, gb);
        __syncthreads();
    }
    if (tid == 0) out[row] = (int)(~(unsigned)(sh_best & 0xFFFFFFFFull));
}

// =================== fallback: proven round-1 single kernel ==================
#define ONT 1024
__global__ __launch_bounds__(ONT, 1)
void sampler_fallback(const float* __restrict__ logits,
                      const float* __restrict__ temps,
                      const float* __restrict__ topps,
                      const float* __restrict__ unoise,
                      int* __restrict__ out)
{
    __shared__ float qmass[NBIN];
    __shared__ float ct[ONT];
    __shared__ float ct2[ONT];
    __shared__ unsigned long long gkeys[GCAP];
    __shared__ float sa[GCAP];
    __shared__ float sb[GCAP];
    __shared__ float wred[16];
    __shared__ unsigned long long sh_cross;
    __shared__ unsigned long long sh_best;
    __shared__ unsigned int gcnt;
    __shared__ int sh_bstar;
    __shared__ float sh_A;
    __shared__ float sh_m;
    __shared__ float sh_Zq;
    __shared__ int sh_kstar;

    const int row = blockIdx.x;
    const int tid = threadIdx.x;
    const float* __restrict__ lrow = logits + (size_t)row * NV;
    const float* __restrict__ urow = unoise + (size_t)row * NV;
    const float invT = 1.0f / temps[row];
    const float topp = topps[row];

    for (int b = tid; b < NBIN; b += ONT) qmass[b] = 0.0f;
    if (tid == 0) { sh_cross = 0ull; sh_best = 0ull; gcnt = 0u; sh_kstar = 0; sh_bstar = 0; sh_A = 0.0f; }
    __syncthreads();

    const float4* __restrict__ l4 = (const float4*)lrow;
    float mloc = -3.402823466e38f;
    const float qscale = 9.5367431640625e-07f;
    for (int v = tid; v < NV4; v += ONT) {
        float4 x = l4[v];
        float xs[4] = {x.x, x.y, x.z, x.w};
        #pragma unroll
        for (int c = 0; c < 4; ++c) {
            float s = xs[c] * invT;
            mloc = fmaxf(mloc, s);
            float q = __expf(s) * qscale;
            float t = fminf(fmaxf(s + 64.0f, 44.0f), 84.0f);
            int bin = (int)((__float_as_uint(t) - BLO) >> BSH);
            bin = min(bin, NBIN - 1);
            atomicAdd(&qmass[bin], q);
        }
    }
    #pragma unroll
    for (int o = 32; o > 0; o >>= 1) mloc = fmaxf(mloc, __shfl_down(mloc, o, 64));
    if ((tid & 63) == 0) wred[tid >> 6] = mloc;
    __syncthreads();
    if (tid < 16) {
        float vv = wred[tid];
        #pragma unroll
        for (int o = 8; o > 0; o >>= 1) vv = fmaxf(vv, __shfl_down(vv, o, 16));
        if (tid == 0) sh_m = vv;
    }
    __syncthreads();
    const float m = sh_m;

    const int b0 = tid * NCH;
    float chs = 0.0f;
    #pragma unroll
    for (int i2 = 0; i2 < NCH; ++i2) {
        int b = b0 + i2;
        if (b < NBIN) chs += qmass[b];
    }
    ct[tid] = chs;
    __syncthreads();
    float* src = ct; float* dst = ct2;
    for (int d = 1; d < ONT; d <<= 1) {
        float val = src[tid] + ((tid + d < ONT) ? src[tid + d] : 0.0f);
        dst[tid] = val;
        __syncthreads();
        float* tm = src; src = dst; dst = tm;
    }
    const float Zq = src[0];
    const float P = topp * Zq;
    {
        float mine = src[tid];
        float nxt = (tid + 1 < ONT) ? src[tid + 1] : 0.0f;
        if (mine > P && nxt <= P)
            atomicMax(&sh_cross, ((unsigned long long)(tid + 1) << 32));
    }
    __syncthreads();
    if (tid == 0) {
        sh_Zq = Zq;
        if (sh_cross == 0ull) { sh_bstar = -1000000; sh_A = 0.0f; }
        else {
            int cstar = (int)(sh_cross >> 32) - 1;
            float run = (cstar + 1 < ONT) ? src[cstar + 1] : 0.0f;
            int bst = -1; float abv = run;
            for (int i2 = NCH - 1; i2 >= 0; --i2) {
                int b = cstar * NCH + i2;
                if (b >= NBIN) continue;
                float inc = qmass[b];
                if (run <= P && run + inc > P) { bst = b; abv = run; break; }
                run += inc;
            }
            if (bst < 0) { bst = cstar * NCH; abv = run; }
            sh_bstar = bst;
            float A = abv;
            if (bst + 1 < NBIN) A -= qmass[bst + 1];
            if (A < 0.0f) A = 0.0f;
            sh_A = A;
        }
    }
    __syncthreads();

    const int bstar = sh_bstar;
    const float Zrow = sh_Zq * 1048576.0f * __expf(-m);
    const float invZrow = 1.0f / Zrow;

    const float4* __restrict__ u4 = (const float4*)urow;
    unsigned long long mybest = 0ull;
    for (int v = tid; v < NV4; v += ONT) {
        float4 x = l4[v];
        float4 uu = u4[v];
        float xs[4] = {x.x, x.y, x.z, x.w};
        float us[4] = {uu.x, uu.y, uu.z, uu.w};
        #pragma unroll
        for (int c = 0; c < 4; ++c) {
            float s = xs[c] * invT;
            float t = fminf(fmaxf(s + 64.0f, 44.0f), 84.0f);
            int bin = (int)((__float_as_uint(t) - BLO) >> BSH);
            bin = min(bin, NBIN - 1);
            if (bin >= bstar + 2) {
                float e = __expf(s - m);
                float noise = fmaxf(-__logf(us[c]), 1e-10f);
                float r = __fdividef(e * invZrow, noise);
                int i = v * 4 + c;
                unsigned long long key = ((unsigned long long)__float_as_uint(r) << 32)
                                       | (unsigned long long)(0xFFFFFFFFu - (unsigned)i);
                if (key > mybest) mybest = key;
            } else if (bin >= bstar - 1) {
                float e = __expf(s - m);
                float p = e / Zrow;
                int i = v * 4 + c;
                unsigned int pos = atomicAdd(&gcnt, 1u);
                if (pos < GCAP)
                    gkeys[pos] = ((unsigned long long)__float_as_uint(p) << 32)
                               | (unsigned long long)(0xFFFFFFFFu - (unsigned)i);
            }
        }
    }
    atomicMax(&sh_best, mybest);
    __syncthreads();

    unsigned int ngu = gcnt; if (ngu > GCAP) ngu = GCAP;
    const int ng = (int)ngu;
    for (int i = tid; i < GCAP; i += ONT) if (i >= ng) gkeys[i] = 0ull;
    __syncthreads();
    if (ng > 0) {
        for (int k = 2; k <= GCAP; k <<= 1) {
            for (int j = k >> 1; j > 0; j >>= 1) {
                for (int i = tid; i < GCAP; i += ONT) {
                    int ixj = i ^ j;
                    if (ixj > i) {
                        unsigned long long a = gkeys[i], b = gkeys[ixj];
                        bool up = ((i & k) == 0);
                        bool sw = up ? (a < b) : (a > b);
                        if (sw) { gkeys[i] = b; gkeys[ixj] = a; }
                    }
                }
                __syncthreads();
            }
        }
        for (int i = tid; i < GCAP; i += ONT)
            sa[i] = __uint_as_float((unsigned)(gkeys[i] >> 32));
        __syncthreads();
        float* ssrc = sa; float* sdst = sb;
        for (int d = 1; d < GCAP; d <<= 1) {
            for (int i = tid; i < GCAP; i += ONT)
                sdst[i] = ssrc[i] + ((i >= d) ? ssrc[i - d] : 0.0f);
            __syncthreads();
            float* tm = ssrc; ssrc = sdst; sdst = tm;
        }
        const float A_p = sh_A / sh_Zq;
        for (int i = tid; i < GCAP; i += ONT) {
            if (i < ng) {
                float excl = (i == 0) ? A_p : (A_p + ssrc[i - 1]);
                if (excl <= topp) atomicMax(&sh_kstar, i + 1);
            }
        }
        __syncthreads();
        const int kst = sh_kstar;
        unsigned long long gb = 0ull;
        for (int i = tid; i < kst; i += ONT) {
            unsigned long long key = gkeys[i];
            unsigned int idx = 0xFFFFFFFFu - (unsigned)(key & 0xFFFFFFFFull);
            float p = __uint_as_float((unsigned)(key >> 32));
            float u = urow[idx];
            float noise = fmaxf(-__logf(u), 1e-10f);
            float r = __fdividef(p, noise);
            unsigned long long k2 = ((unsigned long long)__float_as_uint(r) << 32)
                                  | (unsigned long long)(0xFFFFFFFFu - idx);
            if (k2 > gb) gb = k2;
        }
        atomicMax(&sh_best, gb);
        __syncthreads();
    }
    if (tid == 0) {
        unsigned long long kk = sh_best;
        out[row] = (int)(0xFFFFFFFFu - (unsigned)(kk & 0xFFFFFFFFull));
    }
}

extern "C" void kernel_launch(void* const* d_in, const int* in_sizes, int n_in,
                              void* d_out, int out_size, void* d_ws, size_t ws_size,
                              hipStream_t stream) {
    const float* logits = (const float*)d_in[0];
    const float* temps  = (const float*)d_in[1];
    const float* topps  = (const float*)d_in[2];
    const float* unoise = (const float*)d_in[3];
    int* out = (int*)d_out;

    if (ws_size < WS_NEEDED) {
        hipLaunchKernelGGL(sampler_fallback, dim3(NROW), dim3(ONT), 0, stream,
                           logits, temps, topps, unoise, out);
        return;
    }

    char* ws = (char*)d_ws;
    unsigned* partials = (unsigned*)(ws + WS_PART);
    float* zq   = (float*)(ws + WS_ZQ);
    float* sab  = (float*)(ws + WS_SAB);
    unsigned int* gcnt = (unsigned int*)(ws + WS_GCNT);
    unsigned long long* best = (unsigned long long*)(ws + WS_BEST);
    RowParams* params = (RowParams*)(ws + WS_PARAMS);
    unsigned long long* gather = (unsigned long long*)(ws + WS_GATHER);

    hipMemsetAsync(ws + MEMSET_OFF, 0, MEMSET_BYTES, stream);
    hipLaunchKernelGGL(k1_hist, dim3(NROW * 2), dim3(TPB), 0, stream,
                       logits, temps, partials, zq);
    hipLaunchKernelGGL(k2_scan, dim3(NROW), dim3(TPB), 0, stream,
                       partials, topps, zq, params);
    hipLaunchKernelGGL(k3_race, dim3(NROW * 2), dim3(TPB), 0, stream,
                       logits, temps, unoise, params, best, gcnt, gather, sab);
    hipLaunchKernelGGL(k4_final, dim3(NROW), dim3(TPB), 0, stream,
                       unoise, params, best, gcnt, gather, sab, out);
}

// Round 5
// 156.099 us; speedup vs baseline: 2.2018x; 1.3397x over previous
//
#include <hip/hip_runtime.h>
#include <stdint.h>

#define NROW 256
#define NV   128000
#define NV4  (NV / 4)
#define HALF_F4 (NV4 / 2)       // 16000 float4 per half-row
#define NBIN 7680
#define NCH  8
#define BLO  0x42300000u        // bits of 44.0f
#define BSH  10
#define GCAP 4096
#define LOG2E 1.44269504088896340736f
#define TPB  1024
#define LCAP 2048
#define RMARG 1.005f
#define T_HI_BITS 0x42A7FFFFu   // ~83.99999 -> bin <= 7679
#define NG   2048               // k4 radix groups
#define TCAP 2048               // k4 tie capacity
#define EPT  (GCAP / TPB)       // 4 elements per thread in k4

// ---- workspace layout (bytes) ----
#define PART_BYTES ((size_t)512 * (NBIN / 2) * 4)        // 7,864,320 (packed u16 pairs)
#define WS_PART   0
#define WS_ZQ     (PART_BYTES)                            // 256*8 f32
#define WS_SAB    (WS_ZQ   + (size_t)NROW * 8 * 4)
#define WS_GCNT   (WS_SAB  + (size_t)NROW * 8 * 4)
#define WS_BEST   (WS_GCNT + (size_t)NROW * 8 * 4)
#define WS_PARAMS (WS_BEST + (size_t)NROW * 8)
#define WS_GATHER (WS_PARAMS + (size_t)NROW * 16)
#define WS_NEEDED (WS_GATHER + (size_t)NROW * GCAP * 8)   // = 16,283,648
#define MEMSET_OFF  WS_ZQ
#define MEMSET_BYTES (WS_GATHER - WS_ZQ)
// gu (per-element u_noise for gathered entries) overlays the partials region:
// partials are fully consumed by k2 before k3 writes gu. 256*4096*4 = 4 MB <= 7.86 MB.
#define WS_GU     WS_PART

struct RowParams { int bl; int bh; float P; int pad; };

__device__ __forceinline__ unsigned fenc(float f) {
    unsigned b = __float_as_uint(f);
    return b ^ (((unsigned)((int)b >> 31)) | 0x80000000u);
}
__device__ __forceinline__ float fdec(unsigned e) {
    unsigned m = ((int)e >= 0) ? 0xFFFFFFFFu : 0x80000000u;
    return __uint_as_float(e ^ m);
}

// monotone race key: log2(p/noise) + const = s*log2e - log2(-log2 u) + const
__device__ __forceinline__ unsigned long long race_key(float s, float u, unsigned idx) {
    float nl  = -__builtin_amdgcn_logf(u);
    float l2n = __builtin_amdgcn_logf(nl);
    float keyf = fmaf(s, LOG2E, -l2n);
    return ((unsigned long long)fenc(keyf) << 32) | (unsigned)(~idx);
}

__device__ __forceinline__ int bin_of(float s) {
    float tc = fminf(fmaxf(s + 64.0f, 44.0f), __uint_as_float(T_HI_BITS));
    return (int)((__float_as_uint(tc) - BLO) >> BSH);
}

__device__ __forceinline__ float qval(float s) {       // exp(s) * 2^-20
    return __builtin_amdgcn_exp2f(fmaf(s, LOG2E, -20.0f));
}

__device__ __forceinline__ float cmid(int b) {         // geometric-mid mass of bin b
    float tlo = __uint_as_float(BLO + ((unsigned)b << BSH));
    float thi = __uint_as_float(BLO + ((unsigned)(b + 1) << BSH));
    float tm = 0.5f * (tlo + thi);
    return __builtin_amdgcn_exp2f(fmaf(tm - 64.0f, LOG2E, -20.0f));
}

// ---------------- K1: integer count histogram + exact Zq reduction -----------
__global__ __launch_bounds__(TPB)
void k1_hist(const float* __restrict__ logits, const float* __restrict__ temps,
             unsigned* __restrict__ partials, float* __restrict__ zq)
{
    __shared__ unsigned lh[NBIN];
    __shared__ float wred[16];
    const int row = blockIdx.x >> 1;
    const int sl  = blockIdx.x & 1;
    const int tid = threadIdx.x;
    for (int b = tid; b < NBIN; b += TPB) lh[b] = 0u;
    __syncthreads();
    const float invT = 1.0f / temps[row];
    const float4* __restrict__ l4 =
        (const float4*)(logits + (size_t)row * NV) + sl * HALF_F4;
    float zacc = 0.0f;
    for (int v = tid; v < HALF_F4; v += TPB) {
        float4 x = l4[v];
        float xs[4] = {x.x, x.y, x.z, x.w};
        #pragma unroll
        for (int c = 0; c < 4; ++c) {
            float s = xs[c] * invT;
            atomicAdd(&lh[bin_of(s)], 1u);
            zacc += qval(s);
        }
    }
    #pragma unroll
    for (int o = 32; o > 0; o >>= 1) zacc += __shfl_down(zacc, o, 64);
    if ((tid & 63) == 0) wred[tid >> 6] = zacc;
    __syncthreads();
    if (tid == 0) {
        float z = 0.0f;
        #pragma unroll
        for (int w = 0; w < TPB / 64; ++w) z += wred[w];
        __hip_atomic_fetch_add(&zq[row * 8], z, __ATOMIC_RELAXED,
                               __HIP_MEMORY_SCOPE_AGENT);
    }
    unsigned* __restrict__ pc = partials + (size_t)blockIdx.x * (NBIN / 2);
    for (int pb = tid; pb < NBIN / 2; pb += TPB)
        pc[pb] = (lh[2 * pb] & 0xFFFFu) | (lh[2 * pb + 1] << 16);
}

// ---------------- K2: merge counts, bounded window [bL', bH] -----------------
__global__ __launch_bounds__(TPB)
void k2_scan(const unsigned* __restrict__ partials, const float* __restrict__ topps,
             const float* __restrict__ zq, RowParams* __restrict__ params)
{
    __shared__ float qm[NBIN];    // mass (then per-bin mass suffix)
    __shared__ float qc[NBIN];    // count (then per-bin count suffix)
    __shared__ float ct[TPB];
    __shared__ float ct2[TPB];
    __shared__ int shbH, shbL, shbLp;
    const int row = blockIdx.x, tid = threadIdx.x;
    const unsigned* __restrict__ p0 = partials + (size_t)(row * 2) * (NBIN / 2);
    const unsigned* __restrict__ p1 = p0 + (NBIN / 2);
    for (int pb = tid; pb < NBIN / 2; pb += TPB) {
        unsigned a = p0[pb], b = p1[pb];
        unsigned c0 = (a & 0xFFFFu) + (b & 0xFFFFu);
        unsigned c1 = (a >> 16) + (b >> 16);
        int b0 = 2 * pb, b1 = 2 * pb + 1;
        qc[b0] = (float)c0; qm[b0] = c0 ? (float)c0 * cmid(b0) : 0.0f;
        qc[b1] = (float)c1; qm[b1] = c1 ? (float)c1 * cmid(b1) : 0.0f;
    }
    if (tid == 0) { shbH = NBIN - 1; shbL = 0; }
    __syncthreads();

    // mass: chunk sums -> suffix scan -> per-bin suffix writeback
    float chs = 0.0f;
    if (tid < NBIN / NCH) {
        int b0 = tid * NCH;
        #pragma unroll
        for (int i = 0; i < NCH; ++i) chs += qm[b0 + i];
    }
    ct[tid] = chs;
    __syncthreads();
    float* src = ct; float* dst = ct2;
    for (int d = 1; d < TPB; d <<= 1) {
        float v = src[tid] + ((tid + d < TPB) ? src[tid + d] : 0.0f);
        dst[tid] = v;
        __syncthreads();
        float* tm = src; src = dst; dst = tm;
    }
    {
        float run = (tid + 1 < TPB) ? src[tid + 1] : 0.0f;
        if (tid < NBIN / NCH) {
            int b0 = tid * NCH;
            for (int i = NCH - 1; i >= 0; --i) { run += qm[b0 + i]; qm[b0 + i] = run; }
        }
    }
    __syncthreads();

    // counts: same machinery
    float chc = 0.0f;
    if (tid < NBIN / NCH) {
        int b0 = tid * NCH;
        #pragma unroll
        for (int i = 0; i < NCH; ++i) chc += qc[b0 + i];
    }
    ct[tid] = chc;
    __syncthreads();
    src = ct; dst = ct2;
    for (int d = 1; d < TPB; d <<= 1) {
        float v = src[tid] + ((tid + d < TPB) ? src[tid + d] : 0.0f);
        dst[tid] = v;
        __syncthreads();
        float* tm = src; src = dst; dst = tm;
    }
    {
        float run = (tid + 1 < TPB) ? src[tid + 1] : 0.0f;
        if (tid < NBIN / NCH) {
            int b0 = tid * NCH;
            for (int i = NCH - 1; i >= 0; --i) { run += qc[b0 + i]; qc[b0 + i] = run; }
        }
    }
    __syncthreads();

    const float P = topps[row] * zq[row * 8];
    if (tid < NBIN / NCH) {
        int b0 = tid * NCH;
        for (int i = 0; i < NCH; ++i) {
            int b = b0 + i;
            float Sb  = qm[b];
            float Sb1 = (b + 1 < NBIN) ? qm[b + 1] : 0.0f;
            if (Sb1 * RMARG <= P) atomicMin(&shbH, b);   // bins > bH definitely kept
            if (Sb > RMARG * P)   atomicMax(&shbL, b);   // bins < bL definitely masked
        }
    }
    __syncthreads();
    const int bH = shbH;
    if (tid == 0) shbLp = bH;
    __syncthreads();
    const float target = (float)GCAP + ((bH + 1 < NBIN) ? qc[bH + 1] : 0.0f);
    const int bL = shbL;
    if (tid < NBIN / NCH) {
        int b0 = tid * NCH;
        for (int i = 0; i < NCH; ++i) {
            int b = b0 + i;
            if (b >= bL && qc[b] <= target) atomicMin(&shbLp, b);  // fit in GCAP
        }
    }
    __syncthreads();
    if (tid == 0) {
        RowParams rp; rp.bl = shbLp; rp.bh = bH; rp.P = P; rp.pad = 0;
        params[row] = rp;
    }
}

// ---------------- K3: race over kept, gather window (+u), exact S_above ------
__global__ __launch_bounds__(TPB)
void k3_race(const float* __restrict__ logits, const float* __restrict__ temps,
             const float* __restrict__ unoise, const RowParams* __restrict__ params,
             unsigned long long* __restrict__ best, unsigned int* __restrict__ gcnt,
             unsigned long long* __restrict__ gather, float* __restrict__ gu,
             float* __restrict__ sab)
{
    __shared__ unsigned long long stage[LCAP];
    __shared__ unsigned stageU[LCAP];
    __shared__ unsigned long long wb[16];
    __shared__ float wsab[16];
    __shared__ unsigned int lcnt;
    __shared__ unsigned int sh_base;
    const int row = blockIdx.x >> 1;
    const int sl  = blockIdx.x & 1;
    const int tid = threadIdx.x;
    if (tid == 0) lcnt = 0u;
    __syncthreads();
    const RowParams rp = params[row];
    const int bl = rp.bl, bh = rp.bh;
    const float invT = 1.0f / temps[row];
    const float4* __restrict__ l4 =
        (const float4*)(logits + (size_t)row * NV) + sl * HALF_F4;
    const float4* __restrict__ u4 =
        (const float4*)(unoise + (size_t)row * NV) + sl * HALF_F4;
    unsigned long long* __restrict__ grow = gather + (size_t)row * GCAP;
    float* __restrict__ gurow = gu + (size_t)row * GCAP;
    unsigned int* __restrict__ gcr = &gcnt[row * 8];
    const int ibase = sl * HALF_F4 * 4;
    unsigned long long mybest = 0ull;
    float sabacc = 0.0f;

    for (int v = tid; v < HALF_F4; v += TPB) {
        float4 x = l4[v];
        float4 uu = u4[v];
        float xs[4] = {x.x, x.y, x.z, x.w};
        float us[4] = {uu.x, uu.y, uu.z, uu.w};
        #pragma unroll
        for (int c = 0; c < 4; ++c) {
            float s = xs[c] * invT;
            int bin = bin_of(s);
            unsigned idx = (unsigned)(ibase + v * 4 + c);
            if (bin > bh) {                       // definitely in nucleus
                unsigned long long key = race_key(s, us[c], idx);
                if (key > mybest) mybest = key;
                sabacc += qval(s);
            } else if (bin >= bl) {               // uncertainty window
                unsigned long long ent =
                    ((unsigned long long)fenc(s) << 32) | (unsigned)(~idx);
                unsigned pos = atomicAdd(&lcnt, 1u);
                if (pos < LCAP) { stage[pos] = ent; stageU[pos] = __float_as_uint(us[c]); }
                else {
                    unsigned gp = atomicAdd(gcr, 1u);
                    if (gp < GCAP) { grow[gp] = ent; gurow[gp] = us[c]; }
                }
            }
        }
    }
    #pragma unroll
    for (int o = 32; o > 0; o >>= 1) {
        unsigned long long other = __shfl_down(mybest, o, 64);
        if (other > mybest) mybest = other;
        sabacc += __shfl_down(sabacc, o, 64);
    }
    if ((tid & 63) == 0) { wb[tid >> 6] = mybest; wsab[tid >> 6] = sabacc; }
    __syncthreads();
    if (tid == 0) {
        unsigned long long m2 = wb[0];
        float sz = wsab[0];
        #pragma unroll
        for (int w = 1; w < TPB / 64; ++w) {
            if (wb[w] > m2) m2 = wb[w];
            sz += wsab[w];
        }
        if (m2) atomicMax(&best[row], m2);
        __hip_atomic_fetch_add(&sab[row * 8], sz, __ATOMIC_RELAXED,
                               __HIP_MEMORY_SCOPE_AGENT);
        unsigned int nn = lcnt; if (nn > LCAP) nn = LCAP;
        sh_base = (nn > 0u) ? atomicAdd(gcr, nn) : 0xFFFFFFF0u;
    }
    __syncthreads();
    unsigned int nn = lcnt; if (nn > LCAP) nn = LCAP;
    unsigned int base = sh_base;
    for (unsigned int i = tid; i < nn; i += TPB) {
        unsigned int p = base + i;
        if (p < GCAP) { grow[p] = stage[i]; gurow[p] = __uint_as_float(stageU[i]); }
    }
}

// -------- K4: radix-select crossing group, tiny tie sort, final winner -------
__global__ __launch_bounds__(TPB)
void k4_select(const RowParams* __restrict__ params,
               const unsigned long long* __restrict__ best,
               const unsigned int* __restrict__ gcnt,
               const unsigned long long* __restrict__ gather,
               const float* __restrict__ gu,
               const float* __restrict__ sab, int* __restrict__ out)
{
    __shared__ float ms[NG];
    __shared__ float ssA[NG];
    __shared__ float ssB[NG];
    __shared__ unsigned long long tk[TCAP];
    __shared__ unsigned tu[TCAP];
    __shared__ unsigned long long red_b[16];
    __shared__ int sh_gstar;
    __shared__ unsigned sh_kmin, sh_kmax, sh_tn;
    __shared__ int sh_kst;
    __shared__ float sh_above;
    __shared__ unsigned long long sh_best;

    const int row = blockIdx.x, tid = threadIdx.x;
    const RowParams rp = params[row];
    unsigned n = gcnt[row * 8]; if (n > GCAP) n = GCAP;
    if (tid == 0) {
        sh_best = best[row]; sh_gstar = -1; sh_tn = 0u; sh_kst = 0;
        sh_kmin = 0xFFFFFFFFu; sh_kmax = 0u;
    }
    for (int g = tid; g < NG; g += TPB) ms[g] = 0.0f;
    __syncthreads();

    const unsigned long long* __restrict__ grow = gather + (size_t)row * GCAP;
    const float* __restrict__ gurow = gu + (size_t)row * GCAP;
    unsigned long long e[EPT];
    bool val[EPT];
    unsigned kmn = 0xFFFFFFFFu, kmx = 0u;
    #pragma unroll
    for (int j = 0; j < EPT; ++j) {
        int p = tid + j * TPB;
        val[j] = (unsigned)p < n;
        e[j] = val[j] ? grow[p] : 0ull;
        if (val[j]) {
            unsigned k = (unsigned)(e[j] >> 32);
            kmn = min(kmn, k); kmx = max(kmx, k);
        }
    }
    atomicMin(&sh_kmin, kmn);
    atomicMax(&sh_kmax, kmx);
    __syncthreads();

    const unsigned kmin = sh_kmin;
    const unsigned span = sh_kmax - kmin;
    const int Lb = 32 - __clz(span);            // span==0 -> 0
    const int shft = (Lb > 11) ? (Lb - 11) : 0; // groups <= 2048
    #pragma unroll
    for (int j = 0; j < EPT; ++j) if (val[j]) {
        unsigned key = (unsigned)(e[j] >> 32);
        unsigned g = (key - kmin) >> shft;
        atomicAdd(&ms[g], qval(fdec(key)));
    }
    __syncthreads();

    // inclusive suffix scan over groups: SI[g] = sum_{g' >= g} ms[g']
    for (int g = tid; g < NG; g += TPB) ssA[g] = ms[g];
    __syncthreads();
    float* src = ssA; float* dst = ssB;
    for (int d = 1; d < NG; d <<= 1) {
        for (int g = tid; g < NG; g += TPB)
            dst[g] = src[g] + ((g + d < NG) ? src[g + d] : 0.0f);
        __syncthreads();
        float* tm = src; src = dst; dst = tm;
    }
    const float A = sab[row * 8];
    const float P = rp.P;
    for (int g = tid; g < NG; g += TPB) {
        float SI  = src[g];
        float SI1 = (g + 1 < NG) ? src[g + 1] : 0.0f;
        if (A + SI > P && A + SI1 <= P) atomicMax(&sh_gstar, g);
    }
    __syncthreads();
    const int gstar = sh_gstar;
    if (tid == 0)
        sh_above = A + ((gstar >= 0 && gstar + 1 < NG) ? src[gstar + 1] : 0.0f);

    // kept groups race directly; crossing group stages ties
    unsigned long long mybest = 0ull;
    #pragma unroll
    for (int j = 0; j < EPT; ++j) if (val[j]) {
        unsigned key = (unsigned)(e[j] >> 32);
        int g = (int)((key - kmin) >> shft);
        int p = tid + j * TPB;
        if (gstar < 0 || g > gstar) {
            unsigned idx = ~(unsigned)(e[j] & 0xFFFFFFFFull);
            unsigned long long k2 = race_key(fdec(key), gurow[p], idx);
            if (k2 > mybest) mybest = k2;
        } else if (g == gstar) {
            unsigned t = atomicAdd(&sh_tn, 1u);
            if (t < TCAP) { tk[t] = e[j]; tu[t] = __float_as_uint(gurow[p]); }
        }
    }
    __syncthreads();
    unsigned tn = sh_tn; if (tn > TCAP) tn = TCAP;
    if (gstar >= 0 && tn > 0u) {
        int N2 = 64; while (N2 < (int)tn) N2 <<= 1;
        for (int i = tid; i < N2; i += TPB)
            if (i >= (int)tn) { tk[i] = 0ull; tu[i] = 0u; }
        __syncthreads();
        // bitonic sort descending on (key, ~idx), payload tu
        for (int k = 2; k <= N2; k <<= 1) {
            for (int j2 = k >> 1; j2 > 0; j2 >>= 1) {
                for (int i = tid; i < N2; i += TPB) {
                    int ixj = i ^ j2;
                    if (ixj > i) {
                        unsigned long long a = tk[i], b = tk[ixj];
                        if (((i & k) == 0) ? (a < b) : (a > b)) {
                            tk[i] = b; tk[ixj] = a;
                            unsigned ut = tu[i]; tu[i] = tu[ixj]; tu[ixj] = ut;
                        }
                    }
                }
                __syncthreads();
            }
        }
        // inclusive prefix scan of tie masses
        for (int i = tid; i < N2; i += TPB)
            ssA[i] = (i < (int)tn) ? qval(fdec((unsigned)(tk[i] >> 32))) : 0.0f;
        __syncthreads();
        float* s1 = ssA; float* s2 = ssB;
        for (int d = 1; d < N2; d <<= 1) {
            for (int i = tid; i < N2; i += TPB)
                s2[i] = s1[i] + ((i >= d) ? s1[i - d] : 0.0f);
            __syncthreads();
            float* tm = s1; s1 = s2; s2 = tm;
        }
        const float above = sh_above;
        for (int i = tid; i < (int)tn; i += TPB) {
            float excl = above + ((i == 0) ? 0.0f : s1[i - 1]);
            if (excl <= P) atomicMax(&sh_kst, i + 1);
        }
        __syncthreads();
        const int kst = sh_kst;
        for (int i = tid; i < kst; i += TPB) {
            unsigned idx = ~(unsigned)(tk[i] & 0xFFFFFFFFull);
            unsigned long long k2 =
                race_key(fdec((unsigned)(tk[i] >> 32)), __uint_as_float(tu[i]), idx);
            if (k2 > mybest) mybest = k2;
        }
        __syncthreads();
    }
    #pragma unroll
    for (int o = 32; o > 0; o >>= 1) {
        unsigned long long other = __shfl_down(mybest, o, 64);
        if (other > mybest) mybest = other;
    }
    if ((tid & 63) == 0) red_b[tid >> 6] = mybest;
    __syncthreads();
    if (tid == 0) {
        unsigned long long m2 = sh_best;
        #pragma unroll
        for (int w = 0; w < TPB / 64; ++w) if (red_b[w] > m2) m2 = red_b[w];
        out[row] = (int)(~(unsigned)(m2 & 0xFFFFFFFFull));
    }
}

// =================== fallback: proven round-1 single kernel ==================
#define ONT 1024
__global__ __launch_bounds__(ONT, 1)
void sampler_fallback(const float* __restrict__ logits,
                      const float* __restrict__ temps,
                      const float* __restrict__ topps,
                      const float* __restrict__ unoise,
                      int* __restrict__ out)
{
    __shared__ float qmass[NBIN];
    __shared__ float ct[ONT];
    __shared__ float ct2[ONT];
    __shared__ unsigned long long gkeys[GCAP];
    __shared__ float sa[GCAP];
    __shared__ float sb[GCAP];
    __shared__ float wred[16];
    __shared__ unsigned long long sh_cross;
    __shared__ unsigned long long sh_best;
    __shared__ unsigned int gcnt;
    __shared__ int sh_bstar;
    __shared__ float sh_A;
    __shared__ float sh_m;
    __shared__ float sh_Zq;
    __shared__ int sh_kstar;

    const int row = blockIdx.x;
    const int tid = threadIdx.x;
    const float* __restrict__ lrow = logits + (size_t)row * NV;
    const float* __restrict__ urow = unoise + (size_t)row * NV;
    const float invT = 1.0f / temps[row];
    const float topp = topps[row];

    for (int b = tid; b < NBIN; b += ONT) qmass[b] = 0.0f;
    if (tid == 0) { sh_cross = 0ull; sh_best = 0ull; gcnt = 0u; sh_kstar = 0; sh_bstar = 0; sh_A = 0.0f; }
    __syncthreads();

    const float4* __restrict__ l4 = (const float4*)lrow;
    float mloc = -3.402823466e38f;
    const float qscale = 9.5367431640625e-07f;
    for (int v = tid; v < NV4; v += ONT) {
        float4 x = l4[v];
        float xs[4] = {x.x, x.y, x.z, x.w};
        #pragma unroll
        for (int c = 0; c < 4; ++c) {
            float s = xs[c] * invT;
            mloc = fmaxf(mloc, s);
            float q = __expf(s) * qscale;
            float t = fminf(fmaxf(s + 64.0f, 44.0f), 84.0f);
            int bin = (int)((__float_as_uint(t) - BLO) >> BSH);
            bin = min(bin, NBIN - 1);
            atomicAdd(&qmass[bin], q);
        }
    }
    #pragma unroll
    for (int o = 32; o > 0; o >>= 1) mloc = fmaxf(mloc, __shfl_down(mloc, o, 64));
    if ((tid & 63) == 0) wred[tid >> 6] = mloc;
    __syncthreads();
    if (tid < 16) {
        float vv = wred[tid];
        #pragma unroll
        for (int o = 8; o > 0; o >>= 1) vv = fmaxf(vv, __shfl_down(vv, o, 16));
        if (tid == 0) sh_m = vv;
    }
    __syncthreads();
    const float m = sh_m;

    const int b0 = tid * NCH;
    float chs = 0.0f;
    #pragma unroll
    for (int i2 = 0; i2 < NCH; ++i2) {
        int b = b0 + i2;
        if (b < NBIN) chs += qmass[b];
    }
    ct[tid] = chs;
    __syncthreads();
    float* src = ct; float* dst = ct2;
    for (int d = 1; d < ONT; d <<= 1) {
        float val = src[tid] + ((tid + d < ONT) ? src[tid + d] : 0.0f);
        dst[tid] = val;
        __syncthreads();
        float* tm = src; src = dst; dst = tm;
    }
    const float Zq = src[0];
    const float P = topp * Zq;
    {
        float mine = src[tid];
        float nxt = (tid + 1 < ONT) ? src[tid + 1] : 0.0f;
        if (mine > P && nxt <= P)
            atomicMax(&sh_cross, ((unsigned long long)(tid + 1) << 32));
    }
    __syncthreads();
    if (tid == 0) {
        sh_Zq = Zq;
        if (sh_cross == 0ull) { sh_bstar = -1000000; sh_A = 0.0f; }
        else {
            int cstar = (int)(sh_cross >> 32) - 1;
            float run = (cstar + 1 < ONT) ? src[cstar + 1] : 0.0f;
            int bst = -1; float abv = run;
            for (int i2 = NCH - 1; i2 >= 0; --i2) {
                int b = cstar * NCH + i2;
                if (b >= NBIN) continue;
                float inc = qmass[b];
                if (run <= P && run + inc > P) { bst = b; abv = run; break; }
                run += inc;
            }
            if (bst < 0) { bst = cstar * NCH; abv = run; }
            sh_bstar = bst;
            float A = abv;
            if (bst + 1 < NBIN) A -= qmass[bst + 1];
            if (A < 0.0f) A = 0.0f;
            sh_A = A;
        }
    }
    __syncthreads();

    const int bstar = sh_bstar;
    const float Zrow = sh_Zq * 1048576.0f * __expf(-m);
    const float invZrow = 1.0f / Zrow;

    const float4* __restrict__ u4 = (const float4*)urow;
    unsigned long long mybest = 0ull;
    for (int v = tid; v < NV4; v += ONT) {
        float4 x = l4[v];
        float4 uu = u4[v];
        float xs[4] = {x.x, x.y, x.z, x.w};
        float us[4] = {uu.x, uu.y, uu.z, uu.w};
        #pragma unroll
        for (int c = 0; c < 4; ++c) {
            float s = xs[c] * invT;
            float t = fminf(fmaxf(s + 64.0f, 44.0f), 84.0f);
            int bin = (int)((__float_as_uint(t) - BLO) >> BSH);
            bin = min(bin, NBIN - 1);
            if (bin >= bstar + 2) {
                float e = __expf(s - m);
                float noise = fmaxf(-__logf(us[c]), 1e-10f);
                float r = __fdividef(e * invZrow, noise);
                int i = v * 4 + c;
                unsigned long long key = ((unsigned long long)__float_as_uint(r) << 32)
                                       | (unsigned long long)(0xFFFFFFFFu - (unsigned)i);
                if (key > mybest) mybest = key;
            } else if (bin >= bstar - 1) {
                float e = __expf(s - m);
                float p = e / Zrow;
                int i = v * 4 + c;
                unsigned int pos = atomicAdd(&gcnt, 1u);
                if (pos < GCAP)
                    gkeys[pos] = ((unsigned long long)__float_as_uint(p) << 32)
                               | (unsigned long long)(0xFFFFFFFFu - (unsigned)i);
            }
        }
    }
    atomicMax(&sh_best, mybest);
    __syncthreads();

    unsigned int ngu = gcnt; if (ngu > GCAP) ngu = GCAP;
    const int ng = (int)ngu;
    for (int i = tid; i < GCAP; i += ONT) if (i >= ng) gkeys[i] = 0ull;
    __syncthreads();
    if (ng > 0) {
        for (int k = 2; k <= GCAP; k <<= 1) {
            for (int j = k >> 1; j > 0; j >>= 1) {
                for (int i = tid; i < GCAP; i += ONT) {
                    int ixj = i ^ j;
                    if (ixj > i) {
                        unsigned long long a = gkeys[i], b = gkeys[ixj];
                        bool up = ((i & k) == 0);
                        bool sw = up ? (a < b) : (a > b);
                        if (sw) { gkeys[i] = b; gkeys[ixj] = a; }
                    }
                }
                __syncthreads();
            }
        }
        for (int i = tid; i < GCAP; i += ONT)
            sa[i] = __uint_as_float((unsigned)(gkeys[i] >> 32));
        __syncthreads();
        float* ssrc = sa; float* sdst = sb;
        for (int d = 1; d < GCAP; d <<= 1) {
            for (int i = tid; i < GCAP; i += ONT)
                sdst[i] = ssrc[i] + ((i >= d) ? ssrc[i - d] : 0.0f);
            __syncthreads();
            float* tm = ssrc; ssrc = sdst; sdst = tm;
        }
        const float A_p = sh_A / sh_Zq;
        for (int i = tid; i < GCAP; i += ONT) {
            if (i < ng) {
                float excl = (i == 0) ? A_p : (A_p + ssrc[i - 1]);
                if (excl <= topp) atomicMax(&sh_kstar, i + 1);
            }
        }
        __syncthreads();
        const int kst = sh_kstar;
        unsigned long long gb = 0ull;
        for (int i = tid; i < kst; i += ONT) {
            unsigned long long key = gkeys[i];
            unsigned int idx = 0xFFFFFFFFu - (unsigned)(key & 0xFFFFFFFFull);
            float p = __uint_as_float((unsigned)(key >> 32));
            float u = urow[idx];
            float noise = fmaxf(-__logf(u), 1e-10f);
            float r = __fdividef(p, noise);
            unsigned long long k2 = ((unsigned long long)__float_as_uint(r) << 32)
                                  | (unsigned long long)(0xFFFFFFFFu - idx);
            if (k2 > gb) gb = k2;
        }
        atomicMax(&sh_best, gb);
        __syncthreads();
    }
    if (tid == 0) {
        unsigned long long kk = sh_best;
        out[row] = (int)(0xFFFFFFFFu - (unsigned)(kk & 0xFFFFFFFFull));
    }
}

extern "C" void kernel_launch(void* const* d_in, const int* in_sizes, int n_in,
                              void* d_out, int out_size, void* d_ws, size_t ws_size,
                              hipStream_t stream) {
    const float* logits = (const float*)d_in[0];
    const float* temps  = (const float*)d_in[1];
    const float* topps  = (const float*)d_in[2];
    const float* unoise = (const float*)d_in[3];
    int* out = (int*)d_out;

    if (ws_size < WS_NEEDED) {
        hipLaunchKernelGGL(sampler_fallback, dim3(NROW), dim3(ONT), 0, stream,
                           logits, temps, topps, unoise, out);
        return;
    }

    char* ws = (char*)d_ws;
    unsigned* partials = (unsigned*)(ws + WS_PART);
    float* gu   = (float*)(ws + WS_GU);      // overlays partials (consumed by k2)
    float* zq   = (float*)(ws + WS_ZQ);
    float* sab  = (float*)(ws + WS_SAB);
    unsigned int* gcnt = (unsigned int*)(ws + WS_GCNT);
    unsigned long long* best = (unsigned long long*)(ws + WS_BEST);
    RowParams* params = (RowParams*)(ws + WS_PARAMS);
    unsigned long long* gather = (unsigned long long*)(ws + WS_GATHER);

    hipMemsetAsync(ws + MEMSET_OFF, 0, MEMSET_BYTES, stream);
    hipLaunchKernelGGL(k1_hist, dim3(NROW * 2), dim3(TPB), 0, stream,
                       logits, temps, partials, zq);
    hipLaunchKernelGGL(k2_scan, dim3(NROW), dim3(TPB), 0, stream,
                       partials, topps, zq, params);
    hipLaunchKernelGGL(k3_race, dim3(NROW * 2), dim3(TPB), 0, stream,
                       logits, temps, unoise, params, best, gcnt, gather, gu, sab);
    hipLaunchKernelGGL(k4_select, dim3(NROW), dim3(TPB), 0, stream,
                       params, best, gcnt, gather, gu, sab, out);
}

// Round 6
// 150.071 us; speedup vs baseline: 2.2902x; 1.0402x over previous
//
#include <hip/hip_runtime.h>
#include <stdint.h>

#define NROW 256
#define NV   128000
#define NV4  (NV / 4)
#define HALF_F4 (NV4 / 2)       // 16000 float4 per half-row
#define NBIN 7680
#define NCH  8
#define BLO  0x42300000u        // bits of 44.0f
#define BSH  10
#define GCAP 4096
#define LOG2E 1.44269504088896340736f
#define TPB  1024
#define LCAP 2048
#define RMARG 1.005f
#define T_HI_BITS 0x42A7FFFFu   // ~83.99999 -> bin <= 7679
#define NG   2048               // k4 radix groups
#define TCAP 2048               // k4 tie capacity
#define EPT  (GCAP / TPB)       // 4 elements per thread in k4

// ---- workspace layout (bytes) ----
#define PART_BYTES ((size_t)512 * (NBIN / 2) * 4)        // 7,864,320 (packed u16 pairs)
#define WS_PART   0
#define WS_ZQ     (PART_BYTES)                            // 256*8 f32 (2 slots/row used)
#define WS_SAB    (WS_ZQ   + (size_t)NROW * 8 * 4)
#define WS_GCNT   (WS_SAB  + (size_t)NROW * 8 * 4)
#define WS_BEST   (WS_GCNT + (size_t)NROW * 8 * 4)
#define WS_PARAMS (WS_BEST + (size_t)NROW * 8)
#define WS_GATHER (WS_PARAMS + (size_t)NROW * 16)
#define WS_NEEDED (WS_GATHER + (size_t)NROW * GCAP * 8)   // = 16,283,648
// gu (per-element u_noise for gathered entries) overlays the partials region:
// partials are fully consumed by k2 before k3 writes gu. 256*4096*4 = 4 MB <= 7.86 MB.
#define WS_GU     WS_PART

struct RowParams { int bl; int bh; float P; int pad; };

__device__ __forceinline__ unsigned fenc(float f) {
    unsigned b = __float_as_uint(f);
    return b ^ (((unsigned)((int)b >> 31)) | 0x80000000u);
}
__device__ __forceinline__ float fdec(unsigned e) {
    unsigned m = ((int)e >= 0) ? 0xFFFFFFFFu : 0x80000000u;
    return __uint_as_float(e ^ m);
}

// monotone race key: log2(p/noise) + const = s*log2e - log2(-log2 u) + const
__device__ __forceinline__ unsigned long long race_key(float s, float u, unsigned idx) {
    float nl  = -__builtin_amdgcn_logf(u);
    float l2n = __builtin_amdgcn_logf(nl);
    float keyf = fmaf(s, LOG2E, -l2n);
    return ((unsigned long long)fenc(keyf) << 32) | (unsigned)(~idx);
}

__device__ __forceinline__ int bin_of(float s) {
    float tc = fminf(fmaxf(s + 64.0f, 44.0f), __uint_as_float(T_HI_BITS));
    return (int)((__float_as_uint(tc) - BLO) >> BSH);
}

__device__ __forceinline__ float qval(float s) {       // exp(s) * 2^-20
    return __builtin_amdgcn_exp2f(fmaf(s, LOG2E, -20.0f));
}

__device__ __forceinline__ float cmid(int b) {         // geometric-mid mass of bin b
    float tlo = __uint_as_float(BLO + ((unsigned)b << BSH));
    float thi = __uint_as_float(BLO + ((unsigned)(b + 1) << BSH));
    float tm = 0.5f * (tlo + thi);
    return __builtin_amdgcn_exp2f(fmaf(tm - 64.0f, LOG2E, -20.0f));
}

// ------- K1: integer count histogram + exact Zq reduction + ws init ---------
__global__ __launch_bounds__(TPB)
void k1_hist(const float* __restrict__ logits, const float* __restrict__ temps,
             unsigned* __restrict__ partials, float* __restrict__ zq,
             unsigned int* __restrict__ gcnt, unsigned long long* __restrict__ best)
{
    __shared__ unsigned lh[NBIN];
    __shared__ float wred[16];
    const int row = blockIdx.x >> 1;
    const int sl  = blockIdx.x & 1;
    const int tid = threadIdx.x;
    for (int b = tid; b < NBIN; b += TPB) lh[b] = 0u;
    if (tid == 0 && sl == 0) {              // init for k3 (stream-ordered before it)
        gcnt[row * 8] = 0u;
        best[row] = 0ull;
    }
    __syncthreads();
    const float invT = 1.0f / temps[row];
    const float4* __restrict__ l4 =
        (const float4*)(logits + (size_t)row * NV) + sl * HALF_F4;
    float zacc = 0.0f;
    for (int v = tid; v < HALF_F4; v += TPB) {
        float4 x = l4[v];
        float xs[4] = {x.x, x.y, x.z, x.w};
        #pragma unroll
        for (int c = 0; c < 4; ++c) {
            float s = xs[c] * invT;
            atomicAdd(&lh[bin_of(s)], 1u);
            zacc += qval(s);
        }
    }
    #pragma unroll
    for (int o = 32; o > 0; o >>= 1) zacc += __shfl_down(zacc, o, 64);
    if ((tid & 63) == 0) wred[tid >> 6] = zacc;
    __syncthreads();
    if (tid == 0) {
        float z = 0.0f;
        #pragma unroll
        for (int w = 0; w < TPB / 64; ++w) z += wred[w];
        zq[row * 8 + sl] = z;               // per-slice slot, no atomic, no init
    }
    unsigned* __restrict__ pc = partials + (size_t)blockIdx.x * (NBIN / 2);
    for (int pb = tid; pb < NBIN / 2; pb += TPB)
        pc[pb] = (lh[2 * pb] & 0xFFFFu) | (lh[2 * pb + 1] << 16);
}

// ---------------- K2: merge counts, bounded window [bL', bH] -----------------
__global__ __launch_bounds__(TPB)
void k2_scan(const unsigned* __restrict__ partials, const float* __restrict__ topps,
             const float* __restrict__ zq, RowParams* __restrict__ params)
{
    __shared__ float qm[NBIN];    // mass (then per-bin mass suffix)
    __shared__ float qc[NBIN];    // count (then per-bin count suffix)
    __shared__ float ct[TPB];
    __shared__ float ct2[TPB];
    __shared__ int shbH, shbL, shbLp;
    const int row = blockIdx.x, tid = threadIdx.x;
    const unsigned* __restrict__ p0 = partials + (size_t)(row * 2) * (NBIN / 2);
    const unsigned* __restrict__ p1 = p0 + (NBIN / 2);
    for (int pb = tid; pb < NBIN / 2; pb += TPB) {
        unsigned a = p0[pb], b = p1[pb];
        unsigned c0 = (a & 0xFFFFu) + (b & 0xFFFFu);
        unsigned c1 = (a >> 16) + (b >> 16);
        int b0 = 2 * pb, b1 = 2 * pb + 1;
        qc[b0] = (float)c0; qm[b0] = c0 ? (float)c0 * cmid(b0) : 0.0f;
        qc[b1] = (float)c1; qm[b1] = c1 ? (float)c1 * cmid(b1) : 0.0f;
    }
    if (tid == 0) { shbH = NBIN - 1; shbL = 0; }
    __syncthreads();

    // mass: chunk sums -> suffix scan -> per-bin suffix writeback
    float chs = 0.0f;
    if (tid < NBIN / NCH) {
        int b0 = tid * NCH;
        #pragma unroll
        for (int i = 0; i < NCH; ++i) chs += qm[b0 + i];
    }
    ct[tid] = chs;
    __syncthreads();
    float* src = ct; float* dst = ct2;
    for (int d = 1; d < TPB; d <<= 1) {
        float v = src[tid] + ((tid + d < TPB) ? src[tid + d] : 0.0f);
        dst[tid] = v;
        __syncthreads();
        float* tm = src; src = dst; dst = tm;
    }
    {
        float run = (tid + 1 < TPB) ? src[tid + 1] : 0.0f;
        if (tid < NBIN / NCH) {
            int b0 = tid * NCH;
            for (int i = NCH - 1; i >= 0; --i) { run += qm[b0 + i]; qm[b0 + i] = run; }
        }
    }
    __syncthreads();

    // counts: same machinery
    float chc = 0.0f;
    if (tid < NBIN / NCH) {
        int b0 = tid * NCH;
        #pragma unroll
        for (int i = 0; i < NCH; ++i) chc += qc[b0 + i];
    }
    ct[tid] = chc;
    __syncthreads();
    src = ct; dst = ct2;
    for (int d = 1; d < TPB; d <<= 1) {
        float v = src[tid] + ((tid + d < TPB) ? src[tid + d] : 0.0f);
        dst[tid] = v;
        __syncthreads();
        float* tm = src; src = dst; dst = tm;
    }
    {
        float run = (tid + 1 < TPB) ? src[tid + 1] : 0.0f;
        if (tid < NBIN / NCH) {
            int b0 = tid * NCH;
            for (int i = NCH - 1; i >= 0; --i) { run += qc[b0 + i]; qc[b0 + i] = run; }
        }
    }
    __syncthreads();

    const float P = topps[row] * (zq[row * 8] + zq[row * 8 + 1]);
    if (tid < NBIN / NCH) {
        int b0 = tid * NCH;
        for (int i = 0; i < NCH; ++i) {
            int b = b0 + i;
            float Sb  = qm[b];
            float Sb1 = (b + 1 < NBIN) ? qm[b + 1] : 0.0f;
            if (Sb1 * RMARG <= P) atomicMin(&shbH, b);   // bins > bH definitely kept
            if (Sb > RMARG * P)   atomicMax(&shbL, b);   // bins < bL definitely masked
        }
    }
    __syncthreads();
    const int bH = shbH;
    if (tid == 0) shbLp = bH;
    __syncthreads();
    const float target = (float)GCAP + ((bH + 1 < NBIN) ? qc[bH + 1] : 0.0f);
    const int bL = shbL;
    if (tid < NBIN / NCH) {
        int b0 = tid * NCH;
        for (int i = 0; i < NCH; ++i) {
            int b = b0 + i;
            if (b >= bL && qc[b] <= target) atomicMin(&shbLp, b);  // fit in GCAP
        }
    }
    __syncthreads();
    if (tid == 0) {
        RowParams rp; rp.bl = shbLp; rp.bh = bH; rp.P = P; rp.pad = 0;
        params[row] = rp;
    }
}

// ---------------- K3: race over kept, gather window (+u), exact S_above ------
__global__ __launch_bounds__(TPB)
void k3_race(const float* __restrict__ logits, const float* __restrict__ temps,
             const float* __restrict__ unoise, const RowParams* __restrict__ params,
             unsigned long long* __restrict__ best, unsigned int* __restrict__ gcnt,
             unsigned long long* __restrict__ gather, float* __restrict__ gu,
             float* __restrict__ sab)
{
    __shared__ unsigned long long stage[LCAP];
    __shared__ unsigned stageU[LCAP];
    __shared__ unsigned long long wb[16];
    __shared__ float wsab[16];
    __shared__ unsigned int lcnt;
    __shared__ unsigned int sh_base;
    const int row = blockIdx.x >> 1;
    const int sl  = blockIdx.x & 1;
    const int tid = threadIdx.x;
    if (tid == 0) lcnt = 0u;
    __syncthreads();
    const RowParams rp = params[row];
    const int bl = rp.bl, bh = rp.bh;
    const float invT = 1.0f / temps[row];
    const float4* __restrict__ l4 =
        (const float4*)(logits + (size_t)row * NV) + sl * HALF_F4;
    const float4* __restrict__ u4 =
        (const float4*)(unoise + (size_t)row * NV) + sl * HALF_F4;
    unsigned long long* __restrict__ grow = gather + (size_t)row * GCAP;
    float* __restrict__ gurow = gu + (size_t)row * GCAP;
    unsigned int* __restrict__ gcr = &gcnt[row * 8];
    const int ibase = sl * HALF_F4 * 4;
    unsigned long long mybest = 0ull;
    float sabacc = 0.0f;

    for (int v = tid; v < HALF_F4; v += TPB) {
        float4 x = l4[v];
        float4 uu = u4[v];
        float xs[4] = {x.x, x.y, x.z, x.w};
        float us[4] = {uu.x, uu.y, uu.z, uu.w};
        #pragma unroll
        for (int c = 0; c < 4; ++c) {
            float s = xs[c] * invT;
            int bin = bin_of(s);
            unsigned idx = (unsigned)(ibase + v * 4 + c);
            if (bin > bh) {                       // definitely in nucleus
                unsigned long long key = race_key(s, us[c], idx);
                if (key > mybest) mybest = key;
                sabacc += qval(s);
            } else if (bin >= bl) {               // uncertainty window
                unsigned long long ent =
                    ((unsigned long long)fenc(s) << 32) | (unsigned)(~idx);
                unsigned pos = atomicAdd(&lcnt, 1u);
                if (pos < LCAP) { stage[pos] = ent; stageU[pos] = __float_as_uint(us[c]); }
                else {
                    unsigned gp = atomicAdd(gcr, 1u);
                    if (gp < GCAP) { grow[gp] = ent; gurow[gp] = us[c]; }
                }
            }
        }
    }
    #pragma unroll
    for (int o = 32; o > 0; o >>= 1) {
        unsigned long long other = __shfl_down(mybest, o, 64);
        if (other > mybest) mybest = other;
        sabacc += __shfl_down(sabacc, o, 64);
    }
    if ((tid & 63) == 0) { wb[tid >> 6] = mybest; wsab[tid >> 6] = sabacc; }
    __syncthreads();
    if (tid == 0) {
        unsigned long long m2 = wb[0];
        float sz = wsab[0];
        #pragma unroll
        for (int w = 1; w < TPB / 64; ++w) {
            if (wb[w] > m2) m2 = wb[w];
            sz += wsab[w];
        }
        if (m2) atomicMax(&best[row], m2);
        sab[row * 8 + sl] = sz;               // per-slice slot, no atomic, no init
        unsigned int nn = lcnt; if (nn > LCAP) nn = LCAP;
        sh_base = (nn > 0u) ? atomicAdd(gcr, nn) : 0xFFFFFFF0u;
    }
    __syncthreads();
    unsigned int nn = lcnt; if (nn > LCAP) nn = LCAP;
    unsigned int base = sh_base;
    for (unsigned int i = tid; i < nn; i += TPB) {
        unsigned int p = base + i;
        if (p < GCAP) { grow[p] = stage[i]; gurow[p] = __uint_as_float(stageU[i]); }
    }
}

// -------- K4: radix-select crossing group, tiny tie sort, final winner -------
__global__ __launch_bounds__(TPB)
void k4_select(const RowParams* __restrict__ params,
               const unsigned long long* __restrict__ best,
               const unsigned int* __restrict__ gcnt,
               const unsigned long long* __restrict__ gather,
               const float* __restrict__ gu,
               const float* __restrict__ sab, int* __restrict__ out)
{
    __shared__ float ms[NG];
    __shared__ float ssA[NG];
    __shared__ float ssB[NG];
    __shared__ unsigned long long tk[TCAP];
    __shared__ unsigned tu[TCAP];
    __shared__ unsigned long long red_b[16];
    __shared__ int sh_gstar;
    __shared__ unsigned sh_kmin, sh_kmax, sh_tn;
    __shared__ int sh_kst;
    __shared__ float sh_above;
    __shared__ unsigned long long sh_best;

    const int row = blockIdx.x, tid = threadIdx.x;
    const RowParams rp = params[row];
    unsigned n = gcnt[row * 8]; if (n > GCAP) n = GCAP;
    if (tid == 0) {
        sh_best = best[row]; sh_gstar = -1; sh_tn = 0u; sh_kst = 0;
        sh_kmin = 0xFFFFFFFFu; sh_kmax = 0u;
    }
    for (int g = tid; g < NG; g += TPB) ms[g] = 0.0f;
    __syncthreads();

    const unsigned long long* __restrict__ grow = gather + (size_t)row * GCAP;
    const float* __restrict__ gurow = gu + (size_t)row * GCAP;
    unsigned long long e[EPT];
    bool val[EPT];
    unsigned kmn = 0xFFFFFFFFu, kmx = 0u;
    #pragma unroll
    for (int j = 0; j < EPT; ++j) {
        int p = tid + j * TPB;
        val[j] = (unsigned)p < n;
        e[j] = val[j] ? grow[p] : 0ull;
        if (val[j]) {
            unsigned k = (unsigned)(e[j] >> 32);
            kmn = min(kmn, k); kmx = max(kmx, k);
        }
    }
    atomicMin(&sh_kmin, kmn);
    atomicMax(&sh_kmax, kmx);
    __syncthreads();

    const unsigned kmin = sh_kmin;
    const unsigned span = sh_kmax - kmin;
    const int Lb = 32 - __clz(span);            // span==0 -> 0
    const int shft = (Lb > 11) ? (Lb - 11) : 0; // groups <= 2048
    #pragma unroll
    for (int j = 0; j < EPT; ++j) if (val[j]) {
        unsigned key = (unsigned)(e[j] >> 32);
        unsigned g = (key - kmin) >> shft;
        atomicAdd(&ms[g], qval(fdec(key)));
    }
    __syncthreads();

    // inclusive suffix scan over groups: SI[g] = sum_{g' >= g} ms[g']
    for (int g = tid; g < NG; g += TPB) ssA[g] = ms[g];
    __syncthreads();
    float* src = ssA; float* dst = ssB;
    for (int d = 1; d < NG; d <<= 1) {
        for (int g = tid; g < NG; g += TPB)
            dst[g] = src[g] + ((g + d < NG) ? src[g + d] : 0.0f);
        __syncthreads();
        float* tm = src; src = dst; dst = tm;
    }
    const float A = sab[row * 8] + sab[row * 8 + 1];
    const float P = rp.P;
    for (int g = tid; g < NG; g += TPB) {
        float SI  = src[g];
        float SI1 = (g + 1 < NG) ? src[g + 1] : 0.0f;
        if (A + SI > P && A + SI1 <= P) atomicMax(&sh_gstar, g);
    }
    __syncthreads();
    const int gstar = sh_gstar;
    if (tid == 0)
        sh_above = A + ((gstar >= 0 && gstar + 1 < NG) ? src[gstar + 1] : 0.0f);

    // kept groups race directly; crossing group stages ties
    unsigned long long mybest = 0ull;
    #pragma unroll
    for (int j = 0; j < EPT; ++j) if (val[j]) {
        unsigned key = (unsigned)(e[j] >> 32);
        int g = (int)((key - kmin) >> shft);
        int p = tid + j * TPB;
        if (gstar < 0 || g > gstar) {
            unsigned idx = ~(unsigned)(e[j] & 0xFFFFFFFFull);
            unsigned long long k2 = race_key(fdec(key), gurow[p], idx);
            if (k2 > mybest) mybest = k2;
        } else if (g == gstar) {
            unsigned t = atomicAdd(&sh_tn, 1u);
            if (t < TCAP) { tk[t] = e[j]; tu[t] = __float_as_uint(gurow[p]); }
        }
    }
    __syncthreads();
    unsigned tn = sh_tn; if (tn > TCAP) tn = TCAP;
    if (gstar >= 0 && tn > 0u) {
        int N2 = 64; while (N2 < (int)tn) N2 <<= 1;
        for (int i = tid; i < N2; i += TPB)
            if (i >= (int)tn) { tk[i] = 0ull; tu[i] = 0u; }
        __syncthreads();
        // bitonic sort descending on (key, ~idx), payload tu
        for (int k = 2; k <= N2; k <<= 1) {
            for (int j2 = k >> 1; j2 > 0; j2 >>= 1) {
                for (int i = tid; i < N2; i += TPB) {
                    int ixj = i ^ j2;
                    if (ixj > i) {
                        unsigned long long a = tk[i], b = tk[ixj];
                        if (((i & k) == 0) ? (a < b) : (a > b)) {
                            tk[i] = b; tk[ixj] = a;
                            unsigned ut = tu[i]; tu[i] = tu[ixj]; tu[ixj] = ut;
                        }
                    }
                }
                __syncthreads();
            }
        }
        // inclusive prefix scan of tie masses
        for (int i = tid; i < N2; i += TPB)
            ssA[i] = (i < (int)tn) ? qval(fdec((unsigned)(tk[i] >> 32))) : 0.0f;
        __syncthreads();
        float* s1 = ssA; float* s2 = ssB;
        for (int d = 1; d < N2; d <<= 1) {
            for (int i = tid; i < N2; i += TPB)
                s2[i] = s1[i] + ((i >= d) ? s1[i - d] : 0.0f);
            __syncthreads();
            float* tm = s1; s1 = s2; s2 = tm;
        }
        const float above = sh_above;
        for (int i = tid; i < (int)tn; i += TPB) {
            float excl = above + ((i == 0) ? 0.0f : s1[i - 1]);
            if (excl <= P) atomicMax(&sh_kst, i + 1);
        }
        __syncthreads();
        const int kst = sh_kst;
        for (int i = tid; i < kst; i += TPB) {
            unsigned idx = ~(unsigned)(tk[i] & 0xFFFFFFFFull);
            unsigned long long k2 =
                race_key(fdec((unsigned)(tk[i] >> 32)), __uint_as_float(tu[i]), idx);
            if (k2 > mybest) mybest = k2;
        }
        __syncthreads();
    }
    #pragma unroll
    for (int o = 32; o > 0; o >>= 1) {
        unsigned long long other = __shfl_down(mybest, o, 64);
        if (other > mybest) mybest = other;
    }
    if ((tid & 63) == 0) red_b[tid >> 6] = mybest;
    __syncthreads();
    if (tid == 0) {
        unsigned long long m2 = sh_best;
        #pragma unroll
        for (int w = 0; w < TPB / 64; ++w) if (red_b[w] > m2) m2 = red_b[w];
        out[row] = (int)(~(unsigned)(m2 & 0xFFFFFFFFull));
    }
}

// =================== fallback: proven round-1 single kernel ==================
#define ONT 1024
__global__ __launch_bounds__(ONT, 1)
void sampler_fallback(const float* __restrict__ logits,
                      const float* __restrict__ temps,
                      const float* __restrict__ topps,
                      const float* __restrict__ unoise,
                      int* __restrict__ out)
{
    __shared__ float qmass[NBIN];
    __shared__ float ct[ONT];
    __shared__ float ct2[ONT];
    __shared__ unsigned long long gkeys[GCAP];
    __shared__ float sa[GCAP];
    __shared__ float sb[GCAP];
    __shared__ float wred[16];
    __shared__ unsigned long long sh_cross;
    __shared__ unsigned long long sh_best;
    __shared__ unsigned int gcnt;
    __shared__ int sh_bstar;
    __shared__ float sh_A;
    __shared__ float sh_m;
    __shared__ float sh_Zq;
    __shared__ int sh_kstar;

    const int row = blockIdx.x;
    const int tid = threadIdx.x;
    const float* __restrict__ lrow = logits + (size_t)row * NV;
    const float* __restrict__ urow = unoise + (size_t)row * NV;
    const float invT = 1.0f / temps[row];
    const float topp = topps[row];

    for (int b = tid; b < NBIN; b += ONT) qmass[b] = 0.0f;
    if (tid == 0) { sh_cross = 0ull; sh_best = 0ull; gcnt = 0u; sh_kstar = 0; sh_bstar = 0; sh_A = 0.0f; }
    __syncthreads();

    const float4* __restrict__ l4 = (const float4*)lrow;
    float mloc = -3.402823466e38f;
    const float qscale = 9.5367431640625e-07f;
    for (int v = tid; v < NV4; v += ONT) {
        float4 x = l4[v];
        float xs[4] = {x.x, x.y, x.z, x.w};
        #pragma unroll
        for (int c = 0; c < 4; ++c) {
            float s = xs[c] * invT;
            mloc = fmaxf(mloc, s);
            float q = __expf(s) * qscale;
            float t = fminf(fmaxf(s + 64.0f, 44.0f), 84.0f);
            int bin = (int)((__float_as_uint(t) - BLO) >> BSH);
            bin = min(bin, NBIN - 1);
            atomicAdd(&qmass[bin], q);
        }
    }
    #pragma unroll
    for (int o = 32; o > 0; o >>= 1) mloc = fmaxf(mloc, __shfl_down(mloc, o, 64));
    if ((tid & 63) == 0) wred[tid >> 6] = mloc;
    __syncthreads();
    if (tid < 16) {
        float vv = wred[tid];
        #pragma unroll
        for (int o = 8; o > 0; o >>= 1) vv = fmaxf(vv, __shfl_down(vv, o, 16));
        if (tid == 0) sh_m = vv;
    }
    __syncthreads();
    const float m = sh_m;

    const int b0 = tid * NCH;
    float chs = 0.0f;
    #pragma unroll
    for (int i2 = 0; i2 < NCH; ++i2) {
        int b = b0 + i2;
        if (b < NBIN) chs += qmass[b];
    }
    ct[tid] = chs;
    __syncthreads();
    float* src = ct; float* dst = ct2;
    for (int d = 1; d < ONT; d <<= 1) {
        float val = src[tid] + ((tid + d < ONT) ? src[tid + d] : 0.0f);
        dst[tid] = val;
        __syncthreads();
        float* tm = src; src = dst; dst = tm;
    }
    const float Zq = src[0];
    const float P = topp * Zq;
    {
        float mine = src[tid];
        float nxt = (tid + 1 < ONT) ? src[tid + 1] : 0.0f;
        if (mine > P && nxt <= P)
            atomicMax(&sh_cross, ((unsigned long long)(tid + 1) << 32));
    }
    __syncthreads();
    if (tid == 0) {
        sh_Zq = Zq;
        if (sh_cross == 0ull) { sh_bstar = -1000000; sh_A = 0.0f; }
        else {
            int cstar = (int)(sh_cross >> 32) - 1;
            float run = (cstar + 1 < ONT) ? src[cstar + 1] : 0.0f;
            int bst = -1; float abv = run;
            for (int i2 = NCH - 1; i2 >= 0; --i2) {
                int b = cstar * NCH + i2;
                if (b >= NBIN) continue;
                float inc = qmass[b];
                if (run <= P && run + inc > P) { bst = b; abv = run; break; }
                run += inc;
            }
            if (bst < 0) { bst = cstar * NCH; abv = run; }
            sh_bstar = bst;
            float A = abv;
            if (bst + 1 < NBIN) A -= qmass[bst + 1];
            if (A < 0.0f) A = 0.0f;
            sh_A = A;
        }
    }
    __syncthreads();

    const int bstar = sh_bstar;
    const float Zrow = sh_Zq * 1048576.0f * __expf(-m);
    const float invZrow = 1.0f / Zrow;

    const float4* __restrict__ u4 = (const float4*)urow;
    unsigned long long mybest = 0ull;
    for (int v = tid; v < NV4; v += ONT) {
        float4 x = l4[v];
        float4 uu = u4[v];
        float xs[4] = {x.x, x.y, x.z, x.w};
        float us[4] = {uu.x, uu.y, uu.z, uu.w};
        #pragma unroll
        for (int c = 0; c < 4; ++c) {
            float s = xs[c] * invT;
            float t = fminf(fmaxf(s + 64.0f, 44.0f), 84.0f);
            int bin = (int)((__float_as_uint(t) - BLO) >> BSH);
            bin = min(bin, NBIN - 1);
            if (bin >= bstar + 2) {
                float e = __expf(s - m);
                float noise = fmaxf(-__logf(us[c]), 1e-10f);
                float r = __fdividef(e * invZrow, noise);
                int i = v * 4 + c;
                unsigned long long key = ((unsigned long long)__float_as_uint(r) << 32)
                                       | (unsigned long long)(0xFFFFFFFFu - (unsigned)i);
                if (key > mybest) mybest = key;
            } else if (bin >= bstar - 1) {
                float e = __expf(s - m);
                float p = e / Zrow;
                int i = v * 4 + c;
                unsigned int pos = atomicAdd(&gcnt, 1u);
                if (pos < GCAP)
                    gkeys[pos] = ((unsigned long long)__float_as_uint(p) << 32)
                               | (unsigned long long)(0xFFFFFFFFu - (unsigned)i);
            }
        }
    }
    atomicMax(&sh_best, mybest);
    __syncthreads();

    unsigned int ngu = gcnt; if (ngu > GCAP) ngu = GCAP;
    const int ng = (int)ngu;
    for (int i = tid; i < GCAP; i += ONT) if (i >= ng) gkeys[i] = 0ull;
    __syncthreads();
    if (ng > 0) {
        for (int k = 2; k <= GCAP; k <<= 1) {
            for (int j = k >> 1; j > 0; j >>= 1) {
                for (int i = tid; i < GCAP; i += ONT) {
                    int ixj = i ^ j;
                    if (ixj > i) {
                        unsigned long long a = gkeys[i], b = gkeys[ixj];
                        bool up = ((i & k) == 0);
                        bool sw = up ? (a < b) : (a > b);
                        if (sw) { gkeys[i] = b; gkeys[ixj] = a; }
                    }
                }
                __syncthreads();
            }
        }
        for (int i = tid; i < GCAP; i += ONT)
            sa[i] = __uint_as_float((unsigned)(gkeys[i] >> 32));
        __syncthreads();
        float* ssrc = sa; float* sdst = sb;
        for (int d = 1; d < GCAP; d <<= 1) {
            for (int i = tid; i < GCAP; i += ONT)
                sdst[i] = ssrc[i] + ((i >= d) ? ssrc[i - d] : 0.0f);
            __syncthreads();
            float* tm = ssrc; ssrc = sdst; sdst = tm;
        }
        const float A_p = sh_A / sh_Zq;
        for (int i = tid; i < GCAP; i += ONT) {
            if (i < ng) {
                float excl = (i == 0) ? A_p : (A_p + ssrc[i - 1]);
                if (excl <= topp) atomicMax(&sh_kstar, i + 1);
            }
        }
        __syncthreads();
        const int kst = sh_kstar;
        unsigned long long gb = 0ull;
        for (int i = tid; i < kst; i += ONT) {
            unsigned long long key = gkeys[i];
            unsigned int idx = 0xFFFFFFFFu - (unsigned)(key & 0xFFFFFFFFull);
            float p = __uint_as_float((unsigned)(key >> 32));
            float u = urow[idx];
            float noise = fmaxf(-__logf(u), 1e-10f);
            float r = __fdividef(p, noise);
            unsigned long long k2 = ((unsigned long long)__float_as_uint(r) << 32)
                                  | (unsigned long long)(0xFFFFFFFFu - idx);
            if (k2 > gb) gb = k2;
        }
        atomicMax(&sh_best, gb);
        __syncthreads();
    }
    if (tid == 0) {
        unsigned long long kk = sh_best;
        out[row] = (int)(0xFFFFFFFFu - (unsigned)(kk & 0xFFFFFFFFull));
    }
}

extern "C" void kernel_launch(void* const* d_in, const int* in_sizes, int n_in,
                              void* d_out, int out_size, void* d_ws, size_t ws_size,
                              hipStream_t stream) {
    const float* logits = (const float*)d_in[0];
    const float* temps  = (const float*)d_in[1];
    const float* topps  = (const float*)d_in[2];
    const float* unoise = (const float*)d_in[3];
    int* out = (int*)d_out;

    if (ws_size < WS_NEEDED) {
        hipLaunchKernelGGL(sampler_fallback, dim3(NROW), dim3(ONT), 0, stream,
                           logits, temps, topps, unoise, out);
        return;
    }

    char* ws = (char*)d_ws;
    unsigned* partials = (unsigned*)(ws + WS_PART);
    float* gu   = (float*)(ws + WS_GU);      // overlays partials (consumed by k2)
    float* zq   = (float*)(ws + WS_ZQ);
    float* sab  = (float*)(ws + WS_SAB);
    unsigned int* gcnt = (unsigned int*)(ws + WS_GCNT);
    unsigned long long* best = (unsigned long long*)(ws + WS_BEST);
    RowParams* params = (RowParams*)(ws + WS_PARAMS);
    unsigned long long* gather = (unsigned long long*)(ws + WS_GATHER);

    hipLaunchKernelGGL(k1_hist, dim3(NROW * 2), dim3(TPB), 0, stream,
                       logits, temps, partials, zq, gcnt, best);
    hipLaunchKernelGGL(k2_scan, dim3(NROW), dim3(TPB), 0, stream,
                       partials, topps, zq, params);
    hipLaunchKernelGGL(k3_race, dim3(NROW * 2), dim3(TPB), 0, stream,
                       logits, temps, unoise, params, best, gcnt, gather, gu, sab);
    hipLaunchKernelGGL(k4_select, dim3(NROW), dim3(TPB), 0, stream,
                       params, best, gcnt, gather, gu, sab, out);
}